// Round 8
// baseline (106.631 us; speedup 1.0000x reference)
//
#include <hip/hip_runtime.h>
#include <math.h>

typedef __attribute__((ext_vector_type(8))) short bf16x8;
typedef __attribute__((ext_vector_type(4))) short bf16x4;
typedef __attribute__((ext_vector_type(4))) float f32x4;
typedef __attribute__((ext_vector_type(16))) float f32x16;

#define BB    4
#define SEQ   1024
#define DIMV  512
#define TD    1536
#define NH    8
#define DH    128
#define MROWS (BB*SEQ)

__device__ inline unsigned short f2bf(float x){
    union { float f; unsigned u; } v; v.f = x;
    unsigned r = v.u + 0x7FFF + ((v.u >> 16) & 1);   // RNE
    return (unsigned short)(r >> 16);
}
__device__ inline float bf2f(unsigned short h){
    union { unsigned u; float f; } v; v.u = ((unsigned)h) << 16; return v.f;
}

__device__ inline void glds16(const void* g, void* l){
    __builtin_amdgcn_global_load_lds(
        (const __attribute__((address_space(1))) unsigned int*)g,
        (__attribute__((address_space(3))) unsigned int*)l,
        16, 0, 0);
}

// ---------------- Prep A: x|a -> bf16, K-granule-major ----------------
__global__ __launch_bounds__(256) void prep_a(
    const float* __restrict__ X, const float* __restrict__ A,
    unsigned short* __restrict__ Ab)
{
    const int m   = blockIdx.x*256 + threadIdx.x;
    const int pg  = blockIdx.y;         // p*4+g  (0..63)
    const int mat = blockIdx.z;
    const float* In = mat ? A : X;
    const float* src = In + (size_t)m*DIMV + pg*8;
    float4 v0 = *(const float4*)src;
    float4 v1 = *(const float4*)(src+4);
    float v[8] = {v0.x,v0.y,v0.z,v0.w,v1.x,v1.y,v1.z,v1.w};
    bf16x8 h;
    #pragma unroll
    for (int j=0;j<8;++j) h[j] = (short)f2bf(v[j]);
    const size_t o = ((size_t)(mat*64 + pg)*4096 + m)*8;
    *(bf16x8*)(Ab+o) = h;
}

// ---------------- Prep B: transpose+split W into hi/lo bf16, K-granule-major ----------
__global__ __launch_bounds__(256) void prep_b(
    const float* __restrict__ Wx, const float* __restrict__ Wa,
    unsigned short* __restrict__ Bhi, unsigned short* __restrict__ Blo)
{
    const int n   = blockIdx.x*256 + threadIdx.x;
    const int pg  = blockIdx.y;
    const int mat = blockIdx.z;
    const float* W = mat ? Wa : Wx;
    bf16x8 h, l;
    #pragma unroll
    for (int j=0;j<8;++j){
        float v = W[(size_t)(pg*8 + j)*TD + n];
        unsigned short hb = f2bf(v);
        h[j] = (short)hb;
        l[j] = (short)f2bf(v - bf2f(hb));
    }
    const size_t o = ((size_t)(mat*64 + pg)*1536 + n)*8;
    *(bf16x8*)(Bhi+o) = h;
    *(bf16x8*)(Blo+o) = l;
}

// ---------------- Kernel 1: QKV GEMM via bf16 MFMA, 2-pass (A bf16, W hi/lo) --------
__global__ __launch_bounds__(256,3) void qkv_mfma(
    const unsigned short* __restrict__ Ab,
    const unsigned short* __restrict__ Bhi, const unsigned short* __restrict__ Blo,
    float* __restrict__ wsq, float* __restrict__ wsk,
    unsigned short* __restrict__ Vt)
{
    __shared__ __align__(16) unsigned short sA [4096];
    __shared__ __align__(16) unsigned short sBh[4096];
    __shared__ __align__(16) unsigned short sBl[4096];

    const int mat = blockIdx.z;
    const int bm  = blockIdx.x * 128;
    const int bn  = blockIdx.y * 128;
    const int tid = threadIdx.x;
    const int w   = tid >> 6, l = tid & 63;
    const int wr  = w >> 1,  wc = w & 1;
    const int lg  = l >> 4,  ln = l & 15;

    f32x4 acc[4][4];
    #pragma unroll
    for (int i=0;i<4;++i)
        #pragma unroll
        for (int j=0;j<4;++j){ acc[i][j][0]=0.f; acc[i][j][1]=0.f; acc[i][j][2]=0.f; acc[i][j][3]=0.f; }

    const int g0 = tid >> 7, r0 = tid & 127;
    const size_t ASTEP = (size_t)4*4096*8;
    const size_t BSTEP = (size_t)4*1536*8;
    const unsigned short* a0  = Ab  + ((size_t)(mat*64 + g0)*4096 + bm + r0)*8;
    const unsigned short* a1  = a0 + (size_t)2*4096*8;
    const unsigned short* b0h = Bhi + ((size_t)(mat*64 + g0)*1536 + bn + r0)*8;
    const unsigned short* b0l = Blo + ((size_t)(mat*64 + g0)*1536 + bn + r0)*8;
    const unsigned short* b1h = b0h + (size_t)2*1536*8;
    const unsigned short* b1l = b0l + (size_t)2*1536*8;

    const int d0 = w*512, d1 = 2048 + w*512;

    for (int p=0; p<16; ++p){
        glds16(a0,  sA  + d0);  glds16(a1,  sA  + d1);
        glds16(b0h, sBh + d0);  glds16(b1h, sBh + d1);
        glds16(b0l, sBl + d0);  glds16(b1l, sBl + d1);
        a0 += ASTEP; a1 += ASTEP;
        b0h += BSTEP; b1h += BSTEP; b0l += BSTEP; b1l += BSTEP;
        __syncthreads();

        bf16x8 av[4], bh[4], bl[4];
        #pragma unroll
        for (int mi=0; mi<4; ++mi){
            const int off = (lg*128 + wr*64 + mi*16 + ln)*8;
            av[mi] = *(const bf16x8*)(sA + off);
        }
        #pragma unroll
        for (int ni=0; ni<4; ++ni){
            const int off = (lg*128 + wc*64 + ni*16 + ln)*8;
            bh[ni] = *(const bf16x8*)(sBh + off);
            bl[ni] = *(const bf16x8*)(sBl + off);
        }
        #pragma unroll
        for (int mi=0; mi<4; ++mi)
            #pragma unroll
            for (int ni=0; ni<4; ++ni){
                acc[mi][ni] = __builtin_amdgcn_mfma_f32_16x16x32_bf16(av[mi], bh[ni], acc[mi][ni], 0,0,0);
                acc[mi][ni] = __builtin_amdgcn_mfma_f32_16x16x32_bf16(av[mi], bl[ni], acc[mi][ni], 0,0,0);
            }
        __syncthreads();
    }

    const int b_ = bm >> 10;
    const int n0base = (bm & 1023) + wr*64;
    const int colB = bn + wc*64;
    if (colB < 1024){
        float* base = (colB < 512) ? wsq : wsk;
        #pragma unroll
        for (int ni=0; ni<4; ++ni){
            const int col = colB + ni*16 + ln;
            const int h = mat*4 + ((col >> 7) & 3);
            const int d = col & 127;
            #pragma unroll
            for (int mi=0; mi<4; ++mi){
                const int n0 = n0base + mi*16 + lg*4;
                float* dst = base + ((size_t)(b_*NH + h)*SEQ + n0)*DH + d;
                #pragma unroll
                for (int r=0;r<4;++r) dst[r*DH] = acc[mi][ni][r];
            }
        }
    } else {
        #pragma unroll
        for (int ni=0; ni<4; ++ni){
            const int col = colB + ni*16 + ln;
            const int h = mat*4 + ((col >> 7) & 3);
            const int d = col & 127;
            #pragma unroll
            for (int mi=0; mi<4; ++mi){
                const int n0 = n0base + mi*16 + lg*4;
                unsigned short* dst = Vt + ((size_t)(b_*NH + h)*DH + d)*SEQ + n0;
                bf16x4 pk;
                #pragma unroll
                for (int r=0;r<4;++r) pk[r] = (short)f2bf(acc[mi][ni][r]);
                *(bf16x4*)dst = pk;
            }
        }
    }
}

// ---------------- RoPE cos/sin table ----------------
__global__ __launch_bounds__(256) void rope_tab(float2* __restrict__ tab)
{
    const int i = blockIdx.x*256 + threadIdx.x;   // 65536
    const int n = i >> 6, dd = i & 63;
    const float inv = expf((float)dd * (1.f/64.f) * -9.210340371976184f);
    const float ang = (float)n * inv;
    float sn, cs;
    sincosf(ang, &sn, &cs);
    tab[i] = make_float2(cs, sn);
}

// ---------------- Kernel 2: LayerNorm + RoPE -> bf16 ----------------
__global__ __launch_bounds__(512) void ln_rope(
    const float* __restrict__ wsq, const float* __restrict__ wsk,
    unsigned short* __restrict__ Qb, unsigned short* __restrict__ Kb,
    const float2* __restrict__ tab,
    const float* __restrict__ g_qx, const float* __restrict__ b_qx,
    const float* __restrict__ g_kx, const float* __restrict__ b_kx,
    const float* __restrict__ g_qa, const float* __restrict__ b_qa,
    const float* __restrict__ g_ka, const float* __restrict__ b_ka)
{
    __shared__ float red[16];
    __shared__ float vn[512];
    const int r = blockIdx.x;
    const int which = blockIdx.y;
    const int b_ = r >> 10;
    const int n_ = r & 1023;
    const float* buf = (which & 1) ? wsk : wsq;
    unsigned short* ob = (which & 1) ? Kb : Qb;
    const int h0 = (which >> 1) ? 4 : 0;
    const float* g; const float* bb;
    if (which==0){ g=g_qx; bb=b_qx; }
    else if (which==1){ g=g_kx; bb=b_kx; }
    else if (which==2){ g=g_qa; bb=b_qa; }
    else { g=g_ka; bb=b_ka; }

    const int t = threadIdx.x;
    const int h = h0 + (t >> 7);
    const int d = t & 127;
    const size_t idx = ((size_t)(b_*NH + h)*SEQ + n_)*DH + d;
    float v = buf[idx];
    float s1 = v, s2 = v*v;
    #pragma unroll
    for (int o=32;o>=1;o>>=1){
        s1 += __shfl_down(s1,o);
        s2 += __shfl_down(s2,o);
    }
    const int lane = t & 63, wv = t >> 6;
    if (lane==0){ red[wv]=s1; red[8+wv]=s2; }
    __syncthreads();
    float sum=0.f, sq=0.f;
    #pragma unroll
    for (int w=0;w<8;++w){ sum+=red[w]; sq+=red[8+w]; }
    const float mu = sum * (1.f/512.f);
    const float var = sq * (1.f/512.f) - mu*mu;
    const float rs = rsqrtf(var + 1e-5f);
    const float xn = (v - mu)*rs*g[t] + bb[t];
    vn[t] = xn;
    __syncthreads();
    const float partner = vn[t ^ 64];
    const float2 cssn = tab[(n_ << 6) + (d & 63)];
    const float rot = (d < 64) ? -partner : partner;
    float val = xn*cssn.x + rot*cssn.y;
    // fold 1/sqrt(128) * log2(e) into Q (softmax runs in exp2 domain)
    if (!(which & 1)) val *= 0.08838834764831845f * 1.4426950408889634f;
    ob[idx] = f2bf(val);
}

// ---------------- Kernel 3: 32x32 MFMA flash attention, in-register P ----------------
// 2 waves x 32 q-rows. S^T = mfma32(K,Q): lane owns full q-column (both halves same q).
// P assembled in-register via cvt_pk + permlane32_swap -> PV B-frag, zero P-LDS.
// K/V staged via global_load_lds (pre-swizzled source), double-buffered, 1 barrier/iter.
__global__ __launch_bounds__(128) void attn_mfma(
    const unsigned short* __restrict__ Qb, const unsigned short* __restrict__ Kb,
    const unsigned short* __restrict__ Vt, float* __restrict__ out)
{
    __shared__ __align__(16) unsigned short SMEM[32768];   // 64KB: K0,K1,V0,V1 (16KB each)

    // XCD-aware remap: blocks sharing (b,h) land on one XCD
    const int nblk = blockIdx.x;
    const int jj  = nblk >> 3;
    const int bh  = (nblk & 7)*4 + (jj >> 4);
    const int q0  = (jj & 15) * 64;

    const int tid = threadIdx.x;
    const int w   = tid >> 6;
    const int l   = tid & 63;
    const int lq  = l & 31;      // q column (C/D col); both halves share q
    const int h   = l >> 5;      // k-half within fragments
    const int sw  = l & 7;
    const size_t hoff = (size_t)bh * SEQ * DH;

    // Q fragments: q-row = q0 + w*32 + lq, 8 d-chunks of 16
    bf16x8 qf[8];
    {
        const unsigned short* qp = Qb + hoff + (size_t)(q0 + w*32 + lq)*DH + h*8;
        #pragma unroll
        for (int dc=0;dc<8;++dc) qf[dc] = *(const bf16x8*)(qp + dc*16);
    }

    f32x16 o[4];
    #pragma unroll
    for (int dt=0;dt<4;++dt)
        #pragma unroll
        for (int i=0;i<16;++i) o[dt][i] = 0.f;
    float mrun = -INFINITY, lrun = 0.f;

    const unsigned short* kg0 = Kb + hoff;
    const unsigned short* vg0 = Vt + hoff;
    #define KBUF(b) (SMEM + (b)*8192)
    #define VBUF(b) (SMEM + 16384 + (b)*8192)

    // Stage K (64x128) and V^T (128x64): linear LDS dest, inverse-swizzled source
    #define STAGE_KV(bb, kt) { \
        const unsigned short* kg_ = kg0 + (size_t)(kt)*8192; \
        _Pragma("unroll") \
        for (int i_=0;i_<8;++i_){ \
            int f_ = tid + i_*128; \
            int r_ = f_ >> 4, s_ = f_ & 15; \
            glds16(kg_ + r_*128 + ((s_ ^ (r_&7))*8), KBUF(bb) + f_*8); \
        } \
        _Pragma("unroll") \
        for (int i_=0;i_<8;++i_){ \
            int f_ = tid + i_*128; \
            int dr_ = f_ >> 3, u_ = f_ & 7; \
            glds16(vg0 + (size_t)dr_*SEQ + (kt)*64 + ((u_ ^ (dr_&7))*8), VBUF(bb) + f_*8); \
        } }

    STAGE_KV(0, 0);
    asm volatile("s_waitcnt vmcnt(0)" ::: "memory");
    __builtin_amdgcn_s_barrier();

    int cur = 0;
    for (int kt=0; kt<SEQ/64; ++kt){
        if (kt < SEQ/64 - 1) STAGE_KV(cur^1, kt+1);

        // ---- S^T = K Q^T (32x32x16): s0 = keys ct0(0-31), s1 = keys ct1(32-63) ----
        f32x16 s0, s1;
        #pragma unroll
        for (int i=0;i<16;++i){ s0[i]=0.f; s1[i]=0.f; }
        const unsigned short* kb0 = KBUF(cur) + lq*128;
        const unsigned short* kb1 = KBUF(cur) + (32+lq)*128;
        #pragma unroll
        for (int dc=0;dc<8;++dc){
            const int u = dc*2 + h;
            bf16x8 k0 = *(const bf16x8*)(kb0 + ((u ^ sw)*8));
            bf16x8 k1 = *(const bf16x8*)(kb1 + ((u ^ sw)*8));
            s0 = __builtin_amdgcn_mfma_f32_32x32x16_bf16(k0, qf[dc], s0, 0,0,0);
            s1 = __builtin_amdgcn_mfma_f32_32x32x16_bf16(k1, qf[dc], s1, 0,0,0);
        }

        // ---- in-lane softmax over 32 values + one cross-half exchange ----
        float mx = fmaxf(s0[0], s0[1]);
        #pragma unroll
        for (int i=2;i<16;++i) mx = fmaxf(mx, s0[i]);
        #pragma unroll
        for (int i=0;i<16;++i) mx = fmaxf(mx, s1[i]);
        mx = fmaxf(mx, __shfl_xor(mx, 32));
        if (__any(mx > mrun + 8.f)){
            const float mn = fmaxf(mrun, mx);
            const float al = __builtin_amdgcn_exp2f(mrun - mn);
            mrun = mn; lrun *= al;
            #pragma unroll
            for (int dt=0;dt<4;++dt)
                #pragma unroll
                for (int i=0;i<16;++i) o[dt][i] *= al;
        }
        float p0[16], p1[16];
        float su = 0.f;
        #pragma unroll
        for (int i=0;i<16;++i){ p0[i] = __builtin_amdgcn_exp2f(s0[i]-mrun); su += p0[i]; }
        #pragma unroll
        for (int i=0;i<16;++i){ p1[i] = __builtin_amdgcn_exp2f(s1[i]-mrun); su += p1[i]; }
        su += __shfl_xor(su, 32);
        lrun += su;

        // ---- build PV B-frags in-register (cvt_pk + permlane32_swap) ----
        bf16x8 pf[4];
        #pragma unroll
        for (int ch=0; ch<4; ++ch){
            const float* ps = (ch < 2) ? p0 : p1;
            const int base = (ch & 1)*8;
            unsigned A, Bq, Cq, Dq;
            asm("v_cvt_pk_bf16_f32 %0, %1, %2" : "=v"(A)  : "v"(ps[base+0]), "v"(ps[base+1]));
            asm("v_cvt_pk_bf16_f32 %0, %1, %2" : "=v"(Bq) : "v"(ps[base+2]), "v"(ps[base+3]));
            asm("v_cvt_pk_bf16_f32 %0, %1, %2" : "=v"(Cq) : "v"(ps[base+4]), "v"(ps[base+5]));
            asm("v_cvt_pk_bf16_f32 %0, %1, %2" : "=v"(Dq) : "v"(ps[base+6]), "v"(ps[base+7]));
            // swap vdst-high <-> vsrc-low: A' = keys(8h+0,8h+1), C' = keys(8h+4,8h+5)
            asm("v_permlane32_swap_b32 %0, %1" : "+v"(A), "+v"(Cq));
            asm("v_permlane32_swap_b32 %0, %1" : "+v"(Bq), "+v"(Dq));
            union { unsigned u[4]; bf16x8 v; } pk;
            pk.u[0] = A; pk.u[1] = Bq; pk.u[2] = Cq; pk.u[3] = Dq;
            pf[ch] = pk.v;
        }

        // ---- O^T += V^T P (32x32x16): A=V^T frag, B=P frag ----
        #pragma unroll
        for (int kc=0;kc<4;++kc){
            const int u = kc*2 + h;
            #pragma unroll
            for (int dt=0;dt<4;++dt){
                const unsigned short* vb = VBUF(cur) + (dt*32+lq)*64 + ((u ^ sw)*8);
                bf16x8 vf = *(const bf16x8*)vb;
                o[dt] = __builtin_amdgcn_mfma_f32_32x32x16_bf16(vf, pf[kc], o[dt], 0,0,0);
            }
        }

        if (kt < SEQ/64 - 1){
            asm volatile("s_waitcnt vmcnt(0)" ::: "memory");
            __builtin_amdgcn_s_barrier();
            cur ^= 1;
        }
    }
    #undef STAGE_KV

    // ---- epilogue: transpose O^T through LDS (stride 136, conflict-free) ----
    __syncthreads();   // other wave may still read staged K/V
    float* tl = (float*)SMEM + w*4352;   // 32 rows x 136 floats per wave
    const float linv = 1.0f / lrun;
    #pragma unroll
    for (int dt=0;dt<4;++dt)
        #pragma unroll
        for (int r=0;r<16;++r){
            const int d = dt*32 + (r&3) + 8*(r>>2) + 4*h;
            tl[lq*136 + d] = o[dt][r] * linv;
        }
    __syncthreads();
    const int b_ = bh >> 3, h_ = bh & 7;
    const int row = l >> 1;
    const int n_ = q0 + w*32 + row;
    float* op = out + ((size_t)(b_*SEQ) + n_)*1024 + h_*128 + (l&1)*64;
    const float* tr = tl + row*136 + (l&1)*64;
    #pragma unroll
    for (int c=0;c<16;++c)
        *(float4*)(op + c*4) = *(const float4*)(tr + c*4);
}

extern "C" void kernel_launch(void* const* d_in, const int* in_sizes, int n_in,
                              void* d_out, int out_size, void* d_ws, size_t ws_size,
                              hipStream_t stream) {
    const float* x    = (const float*)d_in[0];
    const float* a    = (const float*)d_in[1];
    const float* Wx   = (const float*)d_in[2];
    const float* Wa   = (const float*)d_in[3];
    const float* g_qx = (const float*)d_in[4];
    const float* b_qx = (const float*)d_in[5];
    const float* g_kx = (const float*)d_in[6];
    const float* b_kx = (const float*)d_in[7];
    const float* g_qa = (const float*)d_in[8];
    const float* b_qa = (const float*)d_in[9];
    const float* g_ka = (const float*)d_in[10];
    const float* b_ka = (const float*)d_in[11];
    float* out = (float*)d_out;

    const size_t E = (size_t)BB*NH*SEQ*DH;        // 4,194,304 elements
    float* wsq = (float*)d_ws;                    // 16MB
    float* wsk = wsq + E;                         // 16MB
    unsigned short* Vt = (unsigned short*)(wsk + E);  // 8MB
    unsigned short* region = Vt + E;              // dual-use
    unsigned short* Ab  = region;                 // 8MB (gemm phase)
    unsigned short* Qb  = region;                 // 8MB (attn phase, overlays Ab)
    unsigned short* Kb  = region + E;             // 8MB
    unsigned short* Bhi = region + 2*E;           // 3MB
    unsigned short* Blo = Bhi + (size_t)2*64*1536*8;  // 3MB
    float2* tab = (float2*)Bhi;                   // 512KB, reuses dead Bhi after GEMM

    prep_a<<<dim3(16, 64, 2), 256, 0, stream>>>(x, a, Ab);
    prep_b<<<dim3(6, 64, 2), 256, 0, stream>>>(Wx, Wa, Bhi, Blo);
    qkv_mfma<<<dim3(32, 12, 2), 256, 0, stream>>>(Ab, Bhi, Blo, wsq, wsk, Vt);
    rope_tab<<<dim3(256), 256, 0, stream>>>(tab);
    ln_rope<<<dim3(MROWS, 4), 512, 0, stream>>>(wsq, wsk, Qb, Kb, tab,
        g_qx, b_qx, g_kx, b_kx, g_qa, b_qa, g_ka, b_ka);
    attn_mfma<<<dim3(512), 128, 0, stream>>>(Qb, Kb, Vt, out);
}

// Round 9
// 103.963 us; speedup vs baseline: 1.0257x; 1.0257x over previous
//
#include <hip/hip_runtime.h>
#include <math.h>

typedef __attribute__((ext_vector_type(8))) short bf16x8;
typedef __attribute__((ext_vector_type(4))) short bf16x4;
typedef __attribute__((ext_vector_type(4))) float f32x4;
typedef __attribute__((ext_vector_type(16))) float f32x16;

#define BB    4
#define SEQ   1024
#define DIMV  512
#define TD    1536
#define NH    8
#define DH    128
#define MROWS (BB*SEQ)

__device__ inline unsigned short f2bf(float x){
    union { float f; unsigned u; } v; v.f = x;
    unsigned r = v.u + 0x7FFF + ((v.u >> 16) & 1);   // RNE
    return (unsigned short)(r >> 16);
}
__device__ inline float bf2f(unsigned short h){
    union { unsigned u; float f; } v; v.u = ((unsigned)h) << 16; return v.f;
}

__device__ inline void glds16(const void* g, void* l){
    __builtin_amdgcn_global_load_lds(
        (const __attribute__((address_space(1))) unsigned int*)g,
        (__attribute__((address_space(3))) unsigned int*)l,
        16, 0, 0);
}

// ---------------- Prep A: x|a -> bf16, K-granule-major ----------------
__global__ __launch_bounds__(256) void prep_a(
    const float* __restrict__ X, const float* __restrict__ A,
    unsigned short* __restrict__ Ab)
{
    const int m   = blockIdx.x*256 + threadIdx.x;
    const int pg  = blockIdx.y;         // p*4+g  (0..63)
    const int mat = blockIdx.z;
    const float* In = mat ? A : X;
    const float* src = In + (size_t)m*DIMV + pg*8;
    float4 v0 = *(const float4*)src;
    float4 v1 = *(const float4*)(src+4);
    float v[8] = {v0.x,v0.y,v0.z,v0.w,v1.x,v1.y,v1.z,v1.w};
    bf16x8 h;
    #pragma unroll
    for (int j=0;j<8;++j) h[j] = (short)f2bf(v[j]);
    const size_t o = ((size_t)(mat*64 + pg)*4096 + m)*8;
    *(bf16x8*)(Ab+o) = h;
}

// ---------------- Prep B: transpose+split W into hi/lo bf16, K-granule-major ----------
__global__ __launch_bounds__(256) void prep_b(
    const float* __restrict__ Wx, const float* __restrict__ Wa,
    unsigned short* __restrict__ Bhi, unsigned short* __restrict__ Blo)
{
    const int n   = blockIdx.x*256 + threadIdx.x;
    const int pg  = blockIdx.y;
    const int mat = blockIdx.z;
    const float* W = mat ? Wa : Wx;
    bf16x8 h, l;
    #pragma unroll
    for (int j=0;j<8;++j){
        float v = W[(size_t)(pg*8 + j)*TD + n];
        unsigned short hb = f2bf(v);
        h[j] = (short)hb;
        l[j] = (short)f2bf(v - bf2f(hb));
    }
    const size_t o = ((size_t)(mat*64 + pg)*1536 + n)*8;
    *(bf16x8*)(Bhi+o) = h;
    *(bf16x8*)(Blo+o) = l;
}

// ---------------- Kernel 1: QKV GEMM via bf16 MFMA, 2-pass (A bf16, W hi/lo) --------
__global__ __launch_bounds__(256,3) void qkv_mfma(
    const unsigned short* __restrict__ Ab,
    const unsigned short* __restrict__ Bhi, const unsigned short* __restrict__ Blo,
    float* __restrict__ wsq, float* __restrict__ wsk,
    unsigned short* __restrict__ Vt)
{
    __shared__ __align__(16) unsigned short sA [4096];
    __shared__ __align__(16) unsigned short sBh[4096];
    __shared__ __align__(16) unsigned short sBl[4096];

    const int mat = blockIdx.z;
    const int bm  = blockIdx.x * 128;
    const int bn  = blockIdx.y * 128;
    const int tid = threadIdx.x;
    const int w   = tid >> 6, l = tid & 63;
    const int wr  = w >> 1,  wc = w & 1;
    const int lg  = l >> 4,  ln = l & 15;

    f32x4 acc[4][4];
    #pragma unroll
    for (int i=0;i<4;++i)
        #pragma unroll
        for (int j=0;j<4;++j){ acc[i][j][0]=0.f; acc[i][j][1]=0.f; acc[i][j][2]=0.f; acc[i][j][3]=0.f; }

    const int g0 = tid >> 7, r0 = tid & 127;
    const size_t ASTEP = (size_t)4*4096*8;
    const size_t BSTEP = (size_t)4*1536*8;
    const unsigned short* a0  = Ab  + ((size_t)(mat*64 + g0)*4096 + bm + r0)*8;
    const unsigned short* a1  = a0 + (size_t)2*4096*8;
    const unsigned short* b0h = Bhi + ((size_t)(mat*64 + g0)*1536 + bn + r0)*8;
    const unsigned short* b0l = Blo + ((size_t)(mat*64 + g0)*1536 + bn + r0)*8;
    const unsigned short* b1h = b0h + (size_t)2*1536*8;
    const unsigned short* b1l = b0l + (size_t)2*1536*8;

    const int d0 = w*512, d1 = 2048 + w*512;

    for (int p=0; p<16; ++p){
        glds16(a0,  sA  + d0);  glds16(a1,  sA  + d1);
        glds16(b0h, sBh + d0);  glds16(b1h, sBh + d1);
        glds16(b0l, sBl + d0);  glds16(b1l, sBl + d1);
        a0 += ASTEP; a1 += ASTEP;
        b0h += BSTEP; b1h += BSTEP; b0l += BSTEP; b1l += BSTEP;
        __syncthreads();

        bf16x8 av[4], bh[4], bl[4];
        #pragma unroll
        for (int mi=0; mi<4; ++mi){
            const int off = (lg*128 + wr*64 + mi*16 + ln)*8;
            av[mi] = *(const bf16x8*)(sA + off);
        }
        #pragma unroll
        for (int ni=0; ni<4; ++ni){
            const int off = (lg*128 + wc*64 + ni*16 + ln)*8;
            bh[ni] = *(const bf16x8*)(sBh + off);
            bl[ni] = *(const bf16x8*)(sBl + off);
        }
        #pragma unroll
        for (int mi=0; mi<4; ++mi)
            #pragma unroll
            for (int ni=0; ni<4; ++ni){
                acc[mi][ni] = __builtin_amdgcn_mfma_f32_16x16x32_bf16(av[mi], bh[ni], acc[mi][ni], 0,0,0);
                acc[mi][ni] = __builtin_amdgcn_mfma_f32_16x16x32_bf16(av[mi], bl[ni], acc[mi][ni], 0,0,0);
            }
        __syncthreads();
    }

    const int b_ = bm >> 10;
    const int n0base = (bm & 1023) + wr*64;
    const int colB = bn + wc*64;
    if (colB < 1024){
        float* base = (colB < 512) ? wsq : wsk;
        #pragma unroll
        for (int ni=0; ni<4; ++ni){
            const int col = colB + ni*16 + ln;
            const int h = mat*4 + ((col >> 7) & 3);
            const int d = col & 127;
            #pragma unroll
            for (int mi=0; mi<4; ++mi){
                const int n0 = n0base + mi*16 + lg*4;
                float* dst = base + ((size_t)(b_*NH + h)*SEQ + n0)*DH + d;
                #pragma unroll
                for (int r=0;r<4;++r) dst[r*DH] = acc[mi][ni][r];
            }
        }
    } else {
        #pragma unroll
        for (int ni=0; ni<4; ++ni){
            const int col = colB + ni*16 + ln;
            const int h = mat*4 + ((col >> 7) & 3);
            const int d = col & 127;
            #pragma unroll
            for (int mi=0; mi<4; ++mi){
                const int n0 = n0base + mi*16 + lg*4;
                unsigned short* dst = Vt + ((size_t)(b_*NH + h)*DH + d)*SEQ + n0;
                bf16x4 pk;
                #pragma unroll
                for (int r=0;r<4;++r) pk[r] = (short)f2bf(acc[mi][ni][r]);
                *(bf16x4*)dst = pk;
            }
        }
    }
}

// ---------------- RoPE cos/sin table ----------------
__global__ __launch_bounds__(256) void rope_tab(float2* __restrict__ tab)
{
    const int i = blockIdx.x*256 + threadIdx.x;   // 65536
    const int n = i >> 6, dd = i & 63;
    const float inv = expf((float)dd * (1.f/64.f) * -9.210340371976184f);
    const float ang = (float)n * inv;
    float sn, cs;
    sincosf(ang, &sn, &cs);
    tab[i] = make_float2(cs, sn);
}

// ---------------- Kernel 2: LayerNorm + RoPE -> bf16 ----------------
__global__ __launch_bounds__(512) void ln_rope(
    const float* __restrict__ wsq, const float* __restrict__ wsk,
    unsigned short* __restrict__ Qb, unsigned short* __restrict__ Kb,
    const float2* __restrict__ tab,
    const float* __restrict__ g_qx, const float* __restrict__ b_qx,
    const float* __restrict__ g_kx, const float* __restrict__ b_kx,
    const float* __restrict__ g_qa, const float* __restrict__ b_qa,
    const float* __restrict__ g_ka, const float* __restrict__ b_ka)
{
    __shared__ float red[16];
    __shared__ float vn[512];
    const int r = blockIdx.x;
    const int which = blockIdx.y;
    const int b_ = r >> 10;
    const int n_ = r & 1023;
    const float* buf = (which & 1) ? wsk : wsq;
    unsigned short* ob = (which & 1) ? Kb : Qb;
    const int h0 = (which >> 1) ? 4 : 0;
    const float* g; const float* bb;
    if (which==0){ g=g_qx; bb=b_qx; }
    else if (which==1){ g=g_kx; bb=b_kx; }
    else if (which==2){ g=g_qa; bb=b_qa; }
    else { g=g_ka; bb=b_ka; }

    const int t = threadIdx.x;
    const int h = h0 + (t >> 7);
    const int d = t & 127;
    const size_t idx = ((size_t)(b_*NH + h)*SEQ + n_)*DH + d;
    float v = buf[idx];
    float s1 = v, s2 = v*v;
    #pragma unroll
    for (int o=32;o>=1;o>>=1){
        s1 += __shfl_down(s1,o);
        s2 += __shfl_down(s2,o);
    }
    const int lane = t & 63, wv = t >> 6;
    if (lane==0){ red[wv]=s1; red[8+wv]=s2; }
    __syncthreads();
    float sum=0.f, sq=0.f;
    #pragma unroll
    for (int w=0;w<8;++w){ sum+=red[w]; sq+=red[8+w]; }
    const float mu = sum * (1.f/512.f);
    const float var = sq * (1.f/512.f) - mu*mu;
    const float rs = rsqrtf(var + 1e-5f);
    const float xn = (v - mu)*rs*g[t] + bb[t];
    vn[t] = xn;
    __syncthreads();
    const float partner = vn[t ^ 64];
    const float2 cssn = tab[(n_ << 6) + (d & 63)];
    const float rot = (d < 64) ? -partner : partner;
    float val = xn*cssn.x + rot*cssn.y;
    // fold 1/sqrt(128) * log2(e) into Q (softmax runs in exp2 domain)
    if (!(which & 1)) val *= 0.08838834764831845f * 1.4426950408889634f;
    ob[idx] = f2bf(val);
}

// ---------------- Kernel 3: 32x32 MFMA flash attention, K-parity split ----------------
// 4 waves (qg, ks): qg = q-group of 32 rows, ks = K-tile parity. Each wave: 16 tiles
// of 32 keys with private (m,l,O^T); epilogue merges parity partials per q-group.
// In-register P via cvt_pk + permlane32_swap. K/V staged via global_load_lds
// (pre-swizzled source), double-buffered per parity, 1 barrier/round.
__global__ __launch_bounds__(256,2) void attn_mfma(
    const unsigned short* __restrict__ Qb, const unsigned short* __restrict__ Kb,
    const unsigned short* __restrict__ Vt, float* __restrict__ out)
{
    __shared__ __align__(16) unsigned short SMEM[32768];   // 64KB

    // XCD-aware remap: blocks sharing (b,h) land on one XCD
    const int nblk = blockIdx.x;
    const int jj  = nblk >> 3;
    const int bh  = (nblk & 7)*4 + (jj >> 4);
    const int q0  = (jj & 15) * 64;

    const int tid = threadIdx.x;
    const int w   = tid >> 6;
    const int qg  = w >> 1;      // q-group: rows q0+qg*32 .. +31
    const int ks  = w & 1;       // K-tile parity
    const int l   = tid & 63;
    const int lq  = l & 31;      // q column (C/D col); both halves same q
    const int h   = l >> 5;      // k-half within fragments
    const size_t hoff = (size_t)bh * SEQ * DH;

    // Q fragments: q-row = q0 + qg*32 + lq, 8 d-chunks of 16
    bf16x8 qf[8];
    {
        const unsigned short* qp = Qb + hoff + (size_t)(q0 + qg*32 + lq)*DH + h*8;
        #pragma unroll
        for (int dc=0;dc<8;++dc) qf[dc] = *(const bf16x8*)(qp + dc*16);
    }

    f32x16 o[4];
    #pragma unroll
    for (int dt=0;dt<4;++dt)
        #pragma unroll
        for (int i=0;i<16;++i) o[dt][i] = 0.f;
    float mrun = -INFINITY, lrun = 0.f;

    const unsigned short* kg0 = Kb + hoff;
    const unsigned short* vg0 = Vt + hoff;

    // K slot (buf,par): SMEM + (buf*2+par)*4096 shorts (32x128 tile, 8KB)
    // V slot (buf,par): SMEM + 16384 + (buf*2+par)*4096 (128x32 V^T tile, 8KB)
    // Stage pair of tiles (2*tp, 2*tp+1): linear LDS dest, inverse-swizzled source.
    #define STAGE_PAIR(bb, tp) { \
        unsigned short* kd0 = SMEM + ((bb)*2+0)*4096; \
        unsigned short* kd1 = SMEM + ((bb)*2+1)*4096; \
        unsigned short* vd0 = SMEM + 16384 + ((bb)*2+0)*4096; \
        unsigned short* vd1 = SMEM + 16384 + ((bb)*2+1)*4096; \
        const unsigned short* ks0_ = kg0 + (size_t)(2*(tp))*4096; \
        const unsigned short* ks1_ = kg0 + (size_t)(2*(tp)+1)*4096; \
        const int vc0_ = (2*(tp))*32, vc1_ = (2*(tp)+1)*32; \
        _Pragma("unroll") \
        for (int i_=0;i_<2;++i_){ \
            int f_ = tid + i_*256; int r_ = f_>>4, s_ = f_&15; \
            glds16(ks0_ + r_*128 + ((s_ ^ (r_&7))*8), kd0 + f_*8); \
        } \
        _Pragma("unroll") \
        for (int i_=0;i_<2;++i_){ \
            int f_ = tid + i_*256; int r_ = f_>>4, s_ = f_&15; \
            glds16(ks1_ + r_*128 + ((s_ ^ (r_&7))*8), kd1 + f_*8); \
        } \
        _Pragma("unroll") \
        for (int i_=0;i_<2;++i_){ \
            int f_ = tid + i_*256; int dr_ = f_>>2, u_ = f_&3; \
            glds16(vg0 + (size_t)dr_*SEQ + vc0_ + ((u_ ^ (dr_&3))*8), vd0 + f_*8); \
        } \
        _Pragma("unroll") \
        for (int i_=0;i_<2;++i_){ \
            int f_ = tid + i_*256; int dr_ = f_>>2, u_ = f_&3; \
            glds16(vg0 + (size_t)dr_*SEQ + vc1_ + ((u_ ^ (dr_&3))*8), vd1 + f_*8); \
        } }

    STAGE_PAIR(0, 0);
    asm volatile("s_waitcnt vmcnt(0)" ::: "memory");
    __builtin_amdgcn_s_barrier();

    const int lsw7 = lq & 7;
    const int lsw3 = lq & 3;
    int cur = 0;
    for (int it=0; it<16; ++it){
        if (it < 15) STAGE_PAIR(cur^1, it+1);

        const unsigned short* kb = SMEM + (cur*2+ks)*4096 + lq*128;
        const unsigned short* vb = SMEM + 16384 + (cur*2+ks)*4096;

        // ---- S^T = K Q^T (32 keys x 32 q) ----
        f32x16 s;
        #pragma unroll
        for (int i=0;i<16;++i) s[i] = 0.f;
        #pragma unroll
        for (int dc=0;dc<8;++dc){
            bf16x8 kf = *(const bf16x8*)(kb + (((dc*2+h) ^ lsw7)*8));
            s = __builtin_amdgcn_mfma_f32_32x32x16_bf16(kf, qf[dc], s, 0,0,0);
        }

        // ---- in-lane softmax over 16 values + cross-half exchange ----
        float mx = fmaxf(s[0], s[1]);
        #pragma unroll
        for (int i=2;i<16;++i) mx = fmaxf(mx, s[i]);
        mx = fmaxf(mx, __shfl_xor(mx, 32));
        if (__any(mx > mrun + 8.f)){
            const float mn = fmaxf(mrun, mx);
            const float al = __builtin_amdgcn_exp2f(mrun - mn);
            mrun = mn; lrun *= al;
            #pragma unroll
            for (int dt=0;dt<4;++dt)
                #pragma unroll
                for (int i=0;i<16;++i) o[dt][i] *= al;
        }
        float su = 0.f;
        #pragma unroll
        for (int i=0;i<16;++i){ s[i] = __builtin_amdgcn_exp2f(s[i]-mrun); su += s[i]; }
        su += __shfl_xor(su, 32);
        lrun += su;

        // ---- build PV B-frags in-register (cvt_pk + permlane32_swap) ----
        bf16x8 pf[2];
        #pragma unroll
        for (int kc=0; kc<2; ++kc){
            const int b8 = kc*8;
            unsigned A, Bq, Cq, Dq;
            asm("v_cvt_pk_bf16_f32 %0, %1, %2" : "=v"(A)  : "v"(s[b8+0]), "v"(s[b8+1]));
            asm("v_cvt_pk_bf16_f32 %0, %1, %2" : "=v"(Bq) : "v"(s[b8+2]), "v"(s[b8+3]));
            asm("v_cvt_pk_bf16_f32 %0, %1, %2" : "=v"(Cq) : "v"(s[b8+4]), "v"(s[b8+5]));
            asm("v_cvt_pk_bf16_f32 %0, %1, %2" : "=v"(Dq) : "v"(s[b8+6]), "v"(s[b8+7]));
            asm("v_permlane32_swap_b32 %0, %1" : "+v"(A),  "+v"(Cq));
            asm("v_permlane32_swap_b32 %0, %1" : "+v"(Bq), "+v"(Dq));
            union { unsigned u[4]; bf16x8 v; } pk;
            pk.u[0] = A; pk.u[1] = Bq; pk.u[2] = Cq; pk.u[3] = Dq;
            pf[kc] = pk.v;
        }

        // ---- O^T += V^T P ----
        #pragma unroll
        for (int kc=0;kc<2;++kc)
            #pragma unroll
            for (int dt=0;dt<4;++dt){
                bf16x8 vf = *(const bf16x8*)(vb + (dt*32+lq)*32 + (((kc*2+h) ^ lsw3)*8));
                o[dt] = __builtin_amdgcn_mfma_f32_32x32x16_bf16(vf, pf[kc], o[dt], 0,0,0);
            }

        if (it < 15){
            asm volatile("s_waitcnt vmcnt(0)" ::: "memory");
            __builtin_amdgcn_s_barrier();
            cur ^= 1;
        }
    }
    #undef STAGE_PAIR

    // ---- epilogue: merge parity partials, transpose, store ----
    __syncthreads();
    float* Lm = (float*)SMEM;            // [2 qg][2 ks][32] running max
    float* Ll = Lm + 128;                // [2 qg][2 ks][32] running sum
    Lm[(qg*2+ks)*32 + lq] = mrun;
    Ll[(qg*2+ks)*32 + lq] = lrun;
    __syncthreads();
    const float mo  = Lm[(qg*2+(ks^1))*32 + lq];
    const float lo_ = Ll[(qg*2+(ks^1))*32 + lq];
    const float mf = fmaxf(mrun, mo);
    const float a  = __builtin_amdgcn_exp2f(mrun - mf);
    const float ao = __builtin_amdgcn_exp2f(mo - mf);
    const float lf = lrun*a + lo_*ao;
    float* Ob = (float*)SMEM + 512 + qg*4160;   // [32 q][stride 129] f32
    if (ks == 1){
        #pragma unroll
        for (int dt=0;dt<4;++dt)
            #pragma unroll
            for (int r=0;r<16;++r){
                const int d = dt*32 + (r&3) + 8*(r>>2) + 4*h;
                Ob[lq*129 + d] = o[dt][r]*a;
            }
    }
    __syncthreads();
    if (ks == 0){
        const float inv = 1.0f/lf;
        #pragma unroll
        for (int dt=0;dt<4;++dt)
            #pragma unroll
            for (int r=0;r<16;++r){
                const int d = dt*32 + (r&3) + 8*(r>>2) + 4*h;
                const int idx = lq*129 + d;
                Ob[idx] = (o[dt][r]*a + Ob[idx])*inv;
            }
    }
    __syncthreads();
    const int b_ = bh >> 3, h_ = bh & 7;
    const int row = tid >> 2, quarter = tid & 3;
    const float* src = (const float*)SMEM + 512 + (row>>5)*4160 + (row&31)*129 + quarter*32;
    float* dst = out + ((size_t)(b_*SEQ) + q0 + row)*1024 + h_*128 + quarter*32;
    #pragma unroll
    for (int j=0;j<8;++j)
        *(float4*)(dst + j*4) = *(const float4*)(src + j*4);
}

extern "C" void kernel_launch(void* const* d_in, const int* in_sizes, int n_in,
                              void* d_out, int out_size, void* d_ws, size_t ws_size,
                              hipStream_t stream) {
    const float* x    = (const float*)d_in[0];
    const float* a    = (const float*)d_in[1];
    const float* Wx   = (const float*)d_in[2];
    const float* Wa   = (const float*)d_in[3];
    const float* g_qx = (const float*)d_in[4];
    const float* b_qx = (const float*)d_in[5];
    const float* g_kx = (const float*)d_in[6];
    const float* b_kx = (const float*)d_in[7];
    const float* g_qa = (const float*)d_in[8];
    const float* b_qa = (const float*)d_in[9];
    const float* g_ka = (const float*)d_in[10];
    const float* b_ka = (const float*)d_in[11];
    float* out = (float*)d_out;

    const size_t E = (size_t)BB*NH*SEQ*DH;        // 4,194,304 elements
    float* wsq = (float*)d_ws;                    // 16MB
    float* wsk = wsq + E;                         // 16MB
    unsigned short* Vt = (unsigned short*)(wsk + E);  // 8MB
    unsigned short* region = Vt + E;              // dual-use
    unsigned short* Ab  = region;                 // 8MB (gemm phase)
    unsigned short* Qb  = region;                 // 8MB (attn phase, overlays Ab)
    unsigned short* Kb  = region + E;             // 8MB
    unsigned short* Bhi = region + 2*E;           // 3MB
    unsigned short* Blo = Bhi + (size_t)2*64*1536*8;  // 3MB
    float2* tab = (float2*)Bhi;                   // 512KB, reuses dead Bhi after GEMM

    prep_a<<<dim3(16, 64, 2), 256, 0, stream>>>(x, a, Ab);
    prep_b<<<dim3(6, 64, 2), 256, 0, stream>>>(Wx, Wa, Bhi, Blo);
    qkv_mfma<<<dim3(32, 12, 2), 256, 0, stream>>>(Ab, Bhi, Blo, wsq, wsk, Vt);
    rope_tab<<<dim3(256), 256, 0, stream>>>(tab);
    ln_rope<<<dim3(MROWS, 4), 512, 0, stream>>>(wsq, wsk, Qb, Kb, tab,
        g_qx, b_qx, g_kx, b_kx, g_qa, b_qa, g_ka, b_ka);
    attn_mfma<<<dim3(512), 256, 0, stream>>>(Qb, Kb, Vt, out);
}

// Round 10
// 97.475 us; speedup vs baseline: 1.0939x; 1.0666x over previous
//
#include <hip/hip_runtime.h>
#include <math.h>

typedef __attribute__((ext_vector_type(8))) short bf16x8;
typedef __attribute__((ext_vector_type(4))) short bf16x4;
typedef __attribute__((ext_vector_type(4))) float f32x4;
typedef __attribute__((ext_vector_type(16))) float f32x16;

#define BB    4
#define SEQ   1024
#define DIMV  512
#define TD    1536
#define NH    8
#define DH    128
#define MROWS (BB*SEQ)

__device__ inline unsigned short f2bf(float x){
    union { float f; unsigned u; } v; v.f = x;
    unsigned r = v.u + 0x7FFF + ((v.u >> 16) & 1);   // RNE
    return (unsigned short)(r >> 16);
}
__device__ inline float bf2f(unsigned short h){
    union { unsigned u; float f; } v; v.u = ((unsigned)h) << 16; return v.f;
}

__device__ inline void glds16(const void* g, void* l){
    __builtin_amdgcn_global_load_lds(
        (const __attribute__((address_space(1))) unsigned int*)g,
        (__attribute__((address_space(3))) unsigned int*)l,
        16, 0, 0);
}

// ---------------- Prep A: x|a -> bf16, K-granule-major ----------------
__global__ __launch_bounds__(256) void prep_a(
    const float* __restrict__ X, const float* __restrict__ A,
    unsigned short* __restrict__ Ab)
{
    const int m   = blockIdx.x*256 + threadIdx.x;
    const int pg  = blockIdx.y;         // p*4+g  (0..63)
    const int mat = blockIdx.z;
    const float* In = mat ? A : X;
    const float* src = In + (size_t)m*DIMV + pg*8;
    float4 v0 = *(const float4*)src;
    float4 v1 = *(const float4*)(src+4);
    float v[8] = {v0.x,v0.y,v0.z,v0.w,v1.x,v1.y,v1.z,v1.w};
    bf16x8 h;
    #pragma unroll
    for (int j=0;j<8;++j) h[j] = (short)f2bf(v[j]);
    const size_t o = ((size_t)(mat*64 + pg)*4096 + m)*8;
    *(bf16x8*)(Ab+o) = h;
}

// ------- Prep B: transpose+split W into hi/lo bf16 (x-block 6 builds RoPE table) -----
__global__ __launch_bounds__(256) void prep_b(
    const float* __restrict__ Wx, const float* __restrict__ Wa,
    unsigned short* __restrict__ Bhi, unsigned short* __restrict__ Blo,
    float2* __restrict__ tab)
{
    if (blockIdx.x == 6){
        const int i = (blockIdx.z*64 + blockIdx.y)*256 + threadIdx.x;   // 0..32767
        #pragma unroll
        for (int k=0;k<2;++k){
            const int idx = i + k*32768;
            const int n = idx >> 6, dd = idx & 63;
            const float inv = expf((float)dd * (1.f/64.f) * -9.210340371976184f);
            const float ang = (float)n * inv;
            float sn, cs;
            sincosf(ang, &sn, &cs);
            tab[idx] = make_float2(cs, sn);
        }
        return;
    }
    const int n   = blockIdx.x*256 + threadIdx.x;
    const int pg  = blockIdx.y;
    const int mat = blockIdx.z;
    const float* W = mat ? Wa : Wx;
    bf16x8 h, l;
    #pragma unroll
    for (int j=0;j<8;++j){
        float v = W[(size_t)(pg*8 + j)*TD + n];
        unsigned short hb = f2bf(v);
        h[j] = (short)hb;
        l[j] = (short)f2bf(v - bf2f(hb));
    }
    const size_t o = ((size_t)(mat*64 + pg)*1536 + n)*8;
    *(bf16x8*)(Bhi+o) = h;
    *(bf16x8*)(Blo+o) = l;
}

// ---------------- Kernel 1: QKV GEMM via bf16 MFMA, 2-pass (A bf16, W hi/lo) --------
// Q/K -> bf16 head layout; V -> bf16 MFMA-fragment-major Vf[bh][tile][kc][dt][lane][8].
__global__ __launch_bounds__(256,3) void qkv_mfma(
    const unsigned short* __restrict__ Ab,
    const unsigned short* __restrict__ Bhi, const unsigned short* __restrict__ Blo,
    unsigned short* __restrict__ wsqb, unsigned short* __restrict__ wskb,
    unsigned short* __restrict__ Vf)
{
    __shared__ __align__(16) unsigned short sA [4096];
    __shared__ __align__(16) unsigned short sBh[4096];
    __shared__ __align__(16) unsigned short sBl[4096];

    const int mat = blockIdx.z;
    const int bm  = blockIdx.x * 128;
    const int bn  = blockIdx.y * 128;
    const int tid = threadIdx.x;
    const int w   = tid >> 6, l = tid & 63;
    const int wr  = w >> 1,  wc = w & 1;
    const int lg  = l >> 4,  ln = l & 15;

    f32x4 acc[4][4];
    #pragma unroll
    for (int i=0;i<4;++i)
        #pragma unroll
        for (int j=0;j<4;++j){ acc[i][j][0]=0.f; acc[i][j][1]=0.f; acc[i][j][2]=0.f; acc[i][j][3]=0.f; }

    const int g0 = tid >> 7, r0 = tid & 127;
    const size_t ASTEP = (size_t)4*4096*8;
    const size_t BSTEP = (size_t)4*1536*8;
    const unsigned short* a0  = Ab  + ((size_t)(mat*64 + g0)*4096 + bm + r0)*8;
    const unsigned short* a1  = a0 + (size_t)2*4096*8;
    const unsigned short* b0h = Bhi + ((size_t)(mat*64 + g0)*1536 + bn + r0)*8;
    const unsigned short* b0l = Blo + ((size_t)(mat*64 + g0)*1536 + bn + r0)*8;
    const unsigned short* b1h = b0h + (size_t)2*1536*8;
    const unsigned short* b1l = b0l + (size_t)2*1536*8;

    const int d0 = w*512, d1 = 2048 + w*512;

    for (int p=0; p<16; ++p){
        glds16(a0,  sA  + d0);  glds16(a1,  sA  + d1);
        glds16(b0h, sBh + d0);  glds16(b1h, sBh + d1);
        glds16(b0l, sBl + d0);  glds16(b1l, sBl + d1);
        a0 += ASTEP; a1 += ASTEP;
        b0h += BSTEP; b1h += BSTEP; b0l += BSTEP; b1l += BSTEP;
        __syncthreads();

        bf16x8 av[4], bh[4], bl[4];
        #pragma unroll
        for (int mi=0; mi<4; ++mi){
            const int off = (lg*128 + wr*64 + mi*16 + ln)*8;
            av[mi] = *(const bf16x8*)(sA + off);
        }
        #pragma unroll
        for (int ni=0; ni<4; ++ni){
            const int off = (lg*128 + wc*64 + ni*16 + ln)*8;
            bh[ni] = *(const bf16x8*)(sBh + off);
            bl[ni] = *(const bf16x8*)(sBl + off);
        }
        #pragma unroll
        for (int mi=0; mi<4; ++mi)
            #pragma unroll
            for (int ni=0; ni<4; ++ni){
                acc[mi][ni] = __builtin_amdgcn_mfma_f32_16x16x32_bf16(av[mi], bh[ni], acc[mi][ni], 0,0,0);
                acc[mi][ni] = __builtin_amdgcn_mfma_f32_16x16x32_bf16(av[mi], bl[ni], acc[mi][ni], 0,0,0);
            }
        __syncthreads();
    }

    const int b_ = bm >> 10;
    const int n0base = (bm & 1023) + wr*64;
    const int colB = bn + wc*64;
    if (colB < 1024){
        unsigned short* base = (colB < 512) ? wsqb : wskb;
        #pragma unroll
        for (int ni=0; ni<4; ++ni){
            const int col = colB + ni*16 + ln;
            const int h = mat*4 + ((col >> 7) & 3);
            const int d = col & 127;
            #pragma unroll
            for (int mi=0; mi<4; ++mi){
                const int n0 = n0base + mi*16 + lg*4;
                unsigned short* dst = base + ((size_t)(b_*NH + h)*SEQ + n0)*DH + d;
                #pragma unroll
                for (int r=0;r<4;++r) dst[r*DH] = f2bf(acc[mi][ni][r]);
            }
        }
    } else {
        // V -> fragment-major: Vf[((bh*32+kt)*2+kc)*4+dt][lane][8]
        #pragma unroll
        for (int ni=0; ni<4; ++ni){
            const int col = colB + ni*16 + ln;
            const int h  = mat*4 + ((col >> 7) & 3);
            const int d  = col & 127;
            const int dt = d >> 5;
            const int lane = (d & 31) + 32*(lg >> 1);
            const int bh = b_*NH + h;
            #pragma unroll
            for (int mi=0; mi<4; ++mi){
                const int kt = (n0base + mi*16) >> 5;
                const int kc = mi & 1;
                unsigned short* dst = Vf +
                    ((((size_t)(bh*32 + kt)*2 + kc)*4 + dt)*64 + lane)*8 + (lg&1)*4;
                bf16x4 pk;
                #pragma unroll
                for (int r=0;r<4;++r) pk[r] = (short)f2bf(acc[mi][ni][r]);
                *(bf16x4*)dst = pk;
            }
        }
    }
}

// ---------------- Kernel 2: LayerNorm + RoPE (bf16 in) -> bf16 ----------------
__global__ __launch_bounds__(512) void ln_rope(
    const unsigned short* __restrict__ wsqb, const unsigned short* __restrict__ wskb,
    unsigned short* __restrict__ Qb, unsigned short* __restrict__ Kb,
    const float2* __restrict__ tab,
    const float* __restrict__ g_qx, const float* __restrict__ b_qx,
    const float* __restrict__ g_kx, const float* __restrict__ b_kx,
    const float* __restrict__ g_qa, const float* __restrict__ b_qa,
    const float* __restrict__ g_ka, const float* __restrict__ b_ka)
{
    __shared__ float red[16];
    __shared__ float vn[512];
    const int r = blockIdx.x;
    const int which = blockIdx.y;
    const int b_ = r >> 10;
    const int n_ = r & 1023;
    const unsigned short* buf = (which & 1) ? wskb : wsqb;
    unsigned short* ob = (which & 1) ? Kb : Qb;
    const int h0 = (which >> 1) ? 4 : 0;
    const float* g; const float* bb;
    if (which==0){ g=g_qx; bb=b_qx; }
    else if (which==1){ g=g_kx; bb=b_kx; }
    else if (which==2){ g=g_qa; bb=b_qa; }
    else { g=g_ka; bb=b_ka; }

    const int t = threadIdx.x;
    const int h = h0 + (t >> 7);
    const int d = t & 127;
    const size_t idx = ((size_t)(b_*NH + h)*SEQ + n_)*DH + d;
    float v = bf2f(buf[idx]);
    float s1 = v, s2 = v*v;
    #pragma unroll
    for (int o=32;o>=1;o>>=1){
        s1 += __shfl_down(s1,o);
        s2 += __shfl_down(s2,o);
    }
    const int lane = t & 63, wv = t >> 6;
    if (lane==0){ red[wv]=s1; red[8+wv]=s2; }
    __syncthreads();
    float sum=0.f, sq=0.f;
    #pragma unroll
    for (int w=0;w<8;++w){ sum+=red[w]; sq+=red[8+w]; }
    const float mu = sum * (1.f/512.f);
    const float var = sq * (1.f/512.f) - mu*mu;
    const float rs = rsqrtf(var + 1e-5f);
    const float xn = (v - mu)*rs*g[t] + bb[t];
    vn[t] = xn;
    __syncthreads();
    const float partner = vn[t ^ 64];
    const float2 cssn = tab[(n_ << 6) + (d & 63)];
    const float rot = (d < 64) ? -partner : partner;
    float val = xn*cssn.x + rot*cssn.y;
    // fold 1/sqrt(128) * log2(e) into Q (softmax runs in exp2 domain)
    if (!(which & 1)) val *= 0.08838834764831845f * 1.4426950408889634f;
    ob[idx] = f2bf(val);
}

// ---------------- Kernel 3: 32x32 MFMA flash attention, reg-V + K-only LDS ----------
// 4 waves (qg, ks). K staged via global_load_lds ring (dbuf), V loaded global->reg
// from fragment-major Vf (coalesced 1KB/instr, L2-resident), double-buffered in regs.
// Counted vmcnt(8) at iter bottom keeps the 8 V loads in flight across the barrier.
__global__ __launch_bounds__(256,2) void attn_mfma(
    const unsigned short* __restrict__ Qb, const unsigned short* __restrict__ Kb,
    const unsigned short* __restrict__ Vf, float* __restrict__ out)
{
    __shared__ __align__(16) unsigned short SMEM[17920];   // 35KB: K ring 32KB / epilogue 35KB

    // XCD-aware remap: blocks sharing (b,h) land on one XCD
    const int nblk = blockIdx.x;
    const int jj  = nblk >> 3;
    const int bh  = (nblk & 7)*4 + (jj >> 4);
    const int q0  = (jj & 15) * 64;

    const int tid = threadIdx.x;
    const int w   = tid >> 6;
    const int qg  = w >> 1;      // q-group: rows q0+qg*32 .. +31
    const int ks  = w & 1;       // K-tile parity
    const int l   = tid & 63;
    const int lq  = l & 31;      // q column / V d-column
    const int h   = l >> 5;      // k-half within fragments
    const size_t hoff = (size_t)bh * SEQ * DH;

    bf16x8 qf[8];
    {
        const unsigned short* qp = Qb + hoff + (size_t)(q0 + qg*32 + lq)*DH + h*8;
        #pragma unroll
        for (int dc=0;dc<8;++dc) qf[dc] = *(const bf16x8*)(qp + dc*16);
    }

    f32x16 o[4];
    #pragma unroll
    for (int dt=0;dt<4;++dt)
        #pragma unroll
        for (int i=0;i<16;++i) o[dt][i] = 0.f;
    float mrun = -INFINITY, lrun = 0.f;

    const unsigned short* kg0 = Kb + hoff;
    const unsigned short* vt0 = Vf + (size_t)bh*32*4096 + l*8;   // per-tile 4096 elems

    // K slot (buf,par): SMEM + (buf*2+par)*4096 shorts (32x128 tile, 8KB).
    #define STAGE_K(bb, tp) { \
        unsigned short* kd0 = SMEM + ((bb)*2+0)*4096; \
        unsigned short* kd1 = SMEM + ((bb)*2+1)*4096; \
        const unsigned short* ks0_ = kg0 + (size_t)(2*(tp))*4096; \
        const unsigned short* ks1_ = kg0 + (size_t)(2*(tp)+1)*4096; \
        _Pragma("unroll") \
        for (int i_=0;i_<2;++i_){ \
            int f_ = tid + i_*256; int r_ = f_>>4, s_ = f_&15; \
            glds16(ks0_ + r_*128 + ((s_ ^ (r_&7))*8), kd0 + f_*8); \
        } \
        _Pragma("unroll") \
        for (int i_=0;i_<2;++i_){ \
            int f_ = tid + i_*256; int r_ = f_>>4, s_ = f_&15; \
            glds16(ks1_ + r_*128 + ((s_ ^ (r_&7))*8), kd1 + f_*8); \
        } }

    #define LOADV(VF_, tile) { \
        const unsigned short* vb_ = vt0 + (size_t)(tile)*4096; \
        _Pragma("unroll") \
        for (int kc_=0;kc_<2;++kc_) \
            _Pragma("unroll") \
            for (int dt_=0;dt_<4;++dt_) \
                VF_[kc_][dt_] = *(const bf16x8*)(vb_ + (kc_*4+dt_)*512); }

    bf16x8 vfA[2][4], vfB[2][4];

    STAGE_K(0, 0);
    LOADV(vfA, ks);
    asm volatile("s_waitcnt vmcnt(0)" ::: "memory");
    __builtin_amdgcn_s_barrier();

    int cur = 0;

    #define BODY(it, VFU, VFL) { \
        if ((it) < 15) STAGE_K(cur^1, (it)+1); \
        __builtin_amdgcn_sched_barrier(0); \
        if ((it) < 15) LOADV(VFL, 2*((it)+1)+ks); \
        const unsigned short* kb = SMEM + (cur*2+ks)*4096 + lq*128; \
        f32x16 s; \
        _Pragma("unroll") \
        for (int i=0;i<16;++i) s[i] = 0.f; \
        _Pragma("unroll") \
        for (int dc=0;dc<8;++dc){ \
            bf16x8 kf = *(const bf16x8*)(kb + (((dc*2+h) ^ (lq&7))*8)); \
            s = __builtin_amdgcn_mfma_f32_32x32x16_bf16(kf, qf[dc], s, 0,0,0); \
        } \
        float mx = fmaxf(s[0], s[1]); \
        _Pragma("unroll") \
        for (int i=2;i<16;++i) mx = fmaxf(mx, s[i]); \
        mx = fmaxf(mx, __shfl_xor(mx, 32)); \
        if (__any(mx > mrun + 8.f)){ \
            const float mn = fmaxf(mrun, mx); \
            const float al = __builtin_amdgcn_exp2f(mrun - mn); \
            mrun = mn; lrun *= al; \
            _Pragma("unroll") \
            for (int dt=0;dt<4;++dt) \
                _Pragma("unroll") \
                for (int i=0;i<16;++i) o[dt][i] *= al; \
        } \
        float su = 0.f; \
        _Pragma("unroll") \
        for (int i=0;i<16;++i){ s[i] = __builtin_amdgcn_exp2f(s[i]-mrun); su += s[i]; } \
        su += __shfl_xor(su, 32); \
        lrun += su; \
        bf16x8 pf[2]; \
        _Pragma("unroll") \
        for (int kc=0; kc<2; ++kc){ \
            const int b8 = kc*8; \
            unsigned A, Bq, Cq, Dq; \
            asm("v_cvt_pk_bf16_f32 %0, %1, %2" : "=v"(A)  : "v"(s[b8+0]), "v"(s[b8+1])); \
            asm("v_cvt_pk_bf16_f32 %0, %1, %2" : "=v"(Bq) : "v"(s[b8+2]), "v"(s[b8+3])); \
            asm("v_cvt_pk_bf16_f32 %0, %1, %2" : "=v"(Cq) : "v"(s[b8+4]), "v"(s[b8+5])); \
            asm("v_cvt_pk_bf16_f32 %0, %1, %2" : "=v"(Dq) : "v"(s[b8+6]), "v"(s[b8+7])); \
            asm("v_permlane32_swap_b32 %0, %1" : "+v"(A),  "+v"(Cq)); \
            asm("v_permlane32_swap_b32 %0, %1" : "+v"(Bq), "+v"(Dq)); \
            union { unsigned u[4]; bf16x8 v; } pk; \
            pk.u[0] = A; pk.u[1] = Bq; pk.u[2] = Cq; pk.u[3] = Dq; \
            pf[kc] = pk.v; \
        } \
        _Pragma("unroll") \
        for (int kc=0;kc<2;++kc) \
            _Pragma("unroll") \
            for (int dt=0;dt<4;++dt) \
                o[dt] = __builtin_amdgcn_mfma_f32_32x32x16_bf16(VFU[kc][dt], pf[kc], o[dt], 0,0,0); \
        if ((it) < 15){ \
            asm volatile("s_waitcnt vmcnt(8)" ::: "memory"); \
            __builtin_amdgcn_s_barrier(); \
            cur ^= 1; \
        } }

    for (int ii=0; ii<8; ++ii){
        BODY(2*ii,   vfA, vfB);
        BODY(2*ii+1, vfB, vfA);
    }
    #undef BODY
    #undef STAGE_K
    #undef LOADV

    // ---- epilogue: merge parity partials, transpose, store ----
    __syncthreads();
    float* Lm = (float*)SMEM;            // [2 qg][2 ks][32] running max
    float* Ll = Lm + 128;                // [2 qg][2 ks][32] running sum
    Lm[(qg*2+ks)*32 + lq] = mrun;
    Ll[(qg*2+ks)*32 + lq] = lrun;
    __syncthreads();
    const float mo  = Lm[(qg*2+(ks^1))*32 + lq];
    const float lo_ = Ll[(qg*2+(ks^1))*32 + lq];
    const float mf = fmaxf(mrun, mo);
    const float a  = __builtin_amdgcn_exp2f(mrun - mf);
    const float ao = __builtin_amdgcn_exp2f(mo - mf);
    const float lf = lrun*a + lo_*ao;
    float* Ob = (float*)SMEM + 512 + qg*4160;   // [32 q][stride 129] f32
    if (ks == 1){
        #pragma unroll
        for (int dt=0;dt<4;++dt)
            #pragma unroll
            for (int r=0;r<16;++r){
                const int d = dt*32 + (r&3) + 8*(r>>2) + 4*h;
                Ob[lq*129 + d] = o[dt][r]*a;
            }
    }
    __syncthreads();
    if (ks == 0){
        const float inv = 1.0f/lf;
        #pragma unroll
        for (int dt=0;dt<4;++dt)
            #pragma unroll
            for (int r=0;r<16;++r){
                const int d = dt*32 + (r&3) + 8*(r>>2) + 4*h;
                const int idx = lq*129 + d;
                Ob[idx] = (o[dt][r]*a + Ob[idx])*inv;
            }
    }
    __syncthreads();
    const int b_ = bh >> 3, h_ = bh & 7;
    const int row = tid >> 2, quarter = tid & 3;
    const float* src = (const float*)SMEM + 512 + (row>>5)*4160 + (row&31)*129 + quarter*32;
    float* dst = out + ((size_t)(b_*SEQ) + q0 + row)*1024 + h_*128 + quarter*32;
    #pragma unroll
    for (int j=0;j<8;++j)
        *(float4*)(dst + j*4) = *(const float4*)(src + j*4);
}

extern "C" void kernel_launch(void* const* d_in, const int* in_sizes, int n_in,
                              void* d_out, int out_size, void* d_ws, size_t ws_size,
                              hipStream_t stream) {
    const float* x    = (const float*)d_in[0];
    const float* a    = (const float*)d_in[1];
    const float* Wx   = (const float*)d_in[2];
    const float* Wa   = (const float*)d_in[3];
    const float* g_qx = (const float*)d_in[4];
    const float* b_qx = (const float*)d_in[5];
    const float* g_kx = (const float*)d_in[6];
    const float* b_kx = (const float*)d_in[7];
    const float* g_qa = (const float*)d_in[8];
    const float* b_qa = (const float*)d_in[9];
    const float* g_ka = (const float*)d_in[10];
    const float* b_ka = (const float*)d_in[11];
    float* out = (float*)d_out;

    const size_t E = (size_t)BB*NH*SEQ*DH;        // 4,194,304 elements
    unsigned short* wsqb = (unsigned short*)d_ws; // 8MB bf16 pre-LN q
    unsigned short* wskb = wsqb + E;              // 8MB bf16 pre-LN k
    unsigned short* Vf   = wskb + E;              // 8MB fragment-major V
    unsigned short* region = Vf + E;
    unsigned short* Ab  = region;                 // 8MB (gemm phase)
    unsigned short* Qb  = region;                 // 8MB (attn phase, overlays Ab)
    unsigned short* Kb  = region + E;             // 8MB
    unsigned short* Bhi = region + 2*E;           // 3MB
    unsigned short* Blo = Bhi + (size_t)2*64*1536*8;  // 3MB
    float2* tab = (float2*)(Blo + (size_t)2*64*1536*8);  // 512KB

    prep_a<<<dim3(16, 64, 2), 256, 0, stream>>>(x, a, Ab);
    prep_b<<<dim3(7, 64, 2), 256, 0, stream>>>(Wx, Wa, Bhi, Blo, tab);
    qkv_mfma<<<dim3(32, 12, 2), 256, 0, stream>>>(Ab, Bhi, Blo, wsqb, wskb, Vf);
    ln_rope<<<dim3(MROWS, 4), 512, 0, stream>>>(wsqb, wskb, Qb, Kb, tab,
        g_qx, b_qx, g_kx, b_kx, g_qa, b_qa, g_ka, b_ka);
    attn_mfma<<<dim3(512), 256, 0, stream>>>(Qb, Kb, Vf, out);
}

// Round 11
// 92.994 us; speedup vs baseline: 1.1466x; 1.0482x over previous
//
#include <hip/hip_runtime.h>
#include <math.h>

typedef __attribute__((ext_vector_type(8))) short bf16x8;
typedef __attribute__((ext_vector_type(4))) short bf16x4;
typedef __attribute__((ext_vector_type(4))) float f32x4;
typedef __attribute__((ext_vector_type(16))) float f32x16;

#define BB    4
#define SEQ   1024
#define DIMV  512
#define TD    1536
#define NH    8
#define DH    128
#define MROWS (BB*SEQ)

__device__ inline unsigned short f2bf(float x){
    union { float f; unsigned u; } v; v.f = x;
    unsigned r = v.u + 0x7FFF + ((v.u >> 16) & 1);   // RNE
    return (unsigned short)(r >> 16);
}
__device__ inline float bf2f(unsigned short h){
    union { unsigned u; float f; } v; v.u = ((unsigned)h) << 16; return v.f;
}

__device__ inline void glds16(const void* g, void* l){
    __builtin_amdgcn_global_load_lds(
        (const __attribute__((address_space(1))) unsigned int*)g,
        (__attribute__((address_space(3))) unsigned int*)l,
        16, 0, 0);
}

// ---------------- Prep A: x|a -> bf16, K-granule-major ----------------
__global__ __launch_bounds__(256) void prep_a(
    const float* __restrict__ X, const float* __restrict__ A,
    unsigned short* __restrict__ Ab)
{
    const int m   = blockIdx.x*256 + threadIdx.x;
    const int pg  = blockIdx.y;         // p*4+g  (0..63)
    const int mat = blockIdx.z;
    const float* In = mat ? A : X;
    const float* src = In + (size_t)m*DIMV + pg*8;
    float4 v0 = *(const float4*)src;
    float4 v1 = *(const float4*)(src+4);
    float v[8] = {v0.x,v0.y,v0.z,v0.w,v1.x,v1.y,v1.z,v1.w};
    bf16x8 h;
    #pragma unroll
    for (int j=0;j<8;++j) h[j] = (short)f2bf(v[j]);
    const size_t o = ((size_t)(mat*64 + pg)*4096 + m)*8;
    *(bf16x8*)(Ab+o) = h;
}

// ------- Prep B: transpose+split W into hi/lo bf16 (x-block 6 builds RoPE table) -----
__global__ __launch_bounds__(256) void prep_b(
    const float* __restrict__ Wx, const float* __restrict__ Wa,
    unsigned short* __restrict__ Bhi, unsigned short* __restrict__ Blo,
    float2* __restrict__ tab)
{
    if (blockIdx.x == 6){
        const int i = (blockIdx.z*64 + blockIdx.y)*256 + threadIdx.x;   // 0..32767
        #pragma unroll
        for (int k=0;k<2;++k){
            const int idx = i + k*32768;
            const int n = idx >> 6, dd = idx & 63;
            const float inv = expf((float)dd * (1.f/64.f) * -9.210340371976184f);
            const float ang = (float)n * inv;
            float sn, cs;
            sincosf(ang, &sn, &cs);
            tab[idx] = make_float2(cs, sn);
        }
        return;
    }
    const int n   = blockIdx.x*256 + threadIdx.x;
    const int pg  = blockIdx.y;
    const int mat = blockIdx.z;
    const float* W = mat ? Wa : Wx;
    bf16x8 h, l;
    #pragma unroll
    for (int j=0;j<8;++j){
        float v = W[(size_t)(pg*8 + j)*TD + n];
        unsigned short hb = f2bf(v);
        h[j] = (short)hb;
        l[j] = (short)f2bf(v - bf2f(hb));
    }
    const size_t o = ((size_t)(mat*64 + pg)*1536 + n)*8;
    *(bf16x8*)(Bhi+o) = h;
    *(bf16x8*)(Blo+o) = l;
}

// ---------------- Kernel 1: QKV GEMM via bf16 MFMA ----------------
// V blocks (bn>=1024): 2-pass W hi/lo (error lands directly in output).
// Q/K blocks (bn<1024): 1-pass bf16 W (error washes out through LN + softmax norm).
__global__ __launch_bounds__(256,3) void qkv_mfma(
    const unsigned short* __restrict__ Ab,
    const unsigned short* __restrict__ Bhi, const unsigned short* __restrict__ Blo,
    unsigned short* __restrict__ wsqb, unsigned short* __restrict__ wskb,
    unsigned short* __restrict__ Vf)
{
    __shared__ __align__(16) unsigned short sA [4096];
    __shared__ __align__(16) unsigned short sBh[4096];
    __shared__ __align__(16) unsigned short sBl[4096];

    const int mat = blockIdx.z;
    const int bm  = blockIdx.x * 128;
    const int bn  = blockIdx.y * 128;
    const bool vblk = (bn >= 1024);
    const int tid = threadIdx.x;
    const int w   = tid >> 6, l = tid & 63;
    const int wr  = w >> 1,  wc = w & 1;
    const int lg  = l >> 4,  ln = l & 15;

    f32x4 acc[4][4];
    #pragma unroll
    for (int i=0;i<4;++i)
        #pragma unroll
        for (int j=0;j<4;++j){ acc[i][j][0]=0.f; acc[i][j][1]=0.f; acc[i][j][2]=0.f; acc[i][j][3]=0.f; }

    const int g0 = tid >> 7, r0 = tid & 127;
    const size_t ASTEP = (size_t)4*4096*8;
    const size_t BSTEP = (size_t)4*1536*8;
    const unsigned short* a0  = Ab  + ((size_t)(mat*64 + g0)*4096 + bm + r0)*8;
    const unsigned short* a1  = a0 + (size_t)2*4096*8;
    const unsigned short* b0h = Bhi + ((size_t)(mat*64 + g0)*1536 + bn + r0)*8;
    const unsigned short* b0l = Blo + ((size_t)(mat*64 + g0)*1536 + bn + r0)*8;
    const unsigned short* b1h = b0h + (size_t)2*1536*8;
    const unsigned short* b1l = b0l + (size_t)2*1536*8;

    const int d0 = w*512, d1 = 2048 + w*512;

    if (vblk){
        for (int p=0; p<16; ++p){
            glds16(a0,  sA  + d0);  glds16(a1,  sA  + d1);
            glds16(b0h, sBh + d0);  glds16(b1h, sBh + d1);
            glds16(b0l, sBl + d0);  glds16(b1l, sBl + d1);
            a0 += ASTEP; a1 += ASTEP;
            b0h += BSTEP; b1h += BSTEP; b0l += BSTEP; b1l += BSTEP;
            __syncthreads();

            bf16x8 av[4], bh[4], bl[4];
            #pragma unroll
            for (int mi=0; mi<4; ++mi){
                const int off = (lg*128 + wr*64 + mi*16 + ln)*8;
                av[mi] = *(const bf16x8*)(sA + off);
            }
            #pragma unroll
            for (int ni=0; ni<4; ++ni){
                const int off = (lg*128 + wc*64 + ni*16 + ln)*8;
                bh[ni] = *(const bf16x8*)(sBh + off);
                bl[ni] = *(const bf16x8*)(sBl + off);
            }
            #pragma unroll
            for (int mi=0; mi<4; ++mi)
                #pragma unroll
                for (int ni=0; ni<4; ++ni){
                    acc[mi][ni] = __builtin_amdgcn_mfma_f32_16x16x32_bf16(av[mi], bh[ni], acc[mi][ni], 0,0,0);
                    acc[mi][ni] = __builtin_amdgcn_mfma_f32_16x16x32_bf16(av[mi], bl[ni], acc[mi][ni], 0,0,0);
                }
            __syncthreads();
        }
    } else {
        for (int p=0; p<16; ++p){
            glds16(a0,  sA  + d0);  glds16(a1,  sA  + d1);
            glds16(b0h, sBh + d0);  glds16(b1h, sBh + d1);
            a0 += ASTEP; a1 += ASTEP;
            b0h += BSTEP; b1h += BSTEP;
            __syncthreads();

            bf16x8 av[4], bh[4];
            #pragma unroll
            for (int mi=0; mi<4; ++mi){
                const int off = (lg*128 + wr*64 + mi*16 + ln)*8;
                av[mi] = *(const bf16x8*)(sA + off);
            }
            #pragma unroll
            for (int ni=0; ni<4; ++ni){
                const int off = (lg*128 + wc*64 + ni*16 + ln)*8;
                bh[ni] = *(const bf16x8*)(sBh + off);
            }
            #pragma unroll
            for (int mi=0; mi<4; ++mi)
                #pragma unroll
                for (int ni=0; ni<4; ++ni)
                    acc[mi][ni] = __builtin_amdgcn_mfma_f32_16x16x32_bf16(av[mi], bh[ni], acc[mi][ni], 0,0,0);
            __syncthreads();
        }
    }

    const int b_ = bm >> 10;
    const int n0base = (bm & 1023) + wr*64;
    const int colB = bn + wc*64;
    if (!vblk){
        unsigned short* base = (colB < 512) ? wsqb : wskb;
        #pragma unroll
        for (int ni=0; ni<4; ++ni){
            const int col = colB + ni*16 + ln;
            const int h = mat*4 + ((col >> 7) & 3);
            const int d = col & 127;
            #pragma unroll
            for (int mi=0; mi<4; ++mi){
                const int n0 = n0base + mi*16 + lg*4;
                unsigned short* dst = base + ((size_t)(b_*NH + h)*SEQ + n0)*DH + d;
                #pragma unroll
                for (int r=0;r<4;++r) dst[r*DH] = f2bf(acc[mi][ni][r]);
            }
        }
    } else {
        // V -> fragment-major: Vf[((bh*32+kt)*2+kc)*4+dt][lane][8]
        #pragma unroll
        for (int ni=0; ni<4; ++ni){
            const int col = colB + ni*16 + ln;
            const int h  = mat*4 + ((col >> 7) & 3);
            const int d  = col & 127;
            const int dt = d >> 5;
            const int lane = (d & 31) + 32*(lg >> 1);
            const int bh = b_*NH + h;
            #pragma unroll
            for (int mi=0; mi<4; ++mi){
                const int kt = (n0base + mi*16) >> 5;
                const int kc = mi & 1;
                unsigned short* dst = Vf +
                    ((((size_t)(bh*32 + kt)*2 + kc)*4 + dt)*64 + lane)*8 + (lg&1)*4;
                bf16x4 pk;
                #pragma unroll
                for (int r=0;r<4;++r) pk[r] = (short)f2bf(acc[mi][ni][r]);
                *(bf16x4*)dst = pk;
            }
        }
    }
}

// ---------------- Kernel 2: LayerNorm + RoPE (bf16 in) -> bf16 ----------------
__global__ __launch_bounds__(512) void ln_rope(
    const unsigned short* __restrict__ wsqb, const unsigned short* __restrict__ wskb,
    unsigned short* __restrict__ Qb, unsigned short* __restrict__ Kb,
    const float2* __restrict__ tab,
    const float* __restrict__ g_qx, const float* __restrict__ b_qx,
    const float* __restrict__ g_kx, const float* __restrict__ b_kx,
    const float* __restrict__ g_qa, const float* __restrict__ b_qa,
    const float* __restrict__ g_ka, const float* __restrict__ b_ka)
{
    __shared__ float red[16];
    __shared__ float vn[512];
    const int r = blockIdx.x;
    const int which = blockIdx.y;
    const int b_ = r >> 10;
    const int n_ = r & 1023;
    const unsigned short* buf = (which & 1) ? wskb : wsqb;
    unsigned short* ob = (which & 1) ? Kb : Qb;
    const int h0 = (which >> 1) ? 4 : 0;
    const float* g; const float* bb;
    if (which==0){ g=g_qx; bb=b_qx; }
    else if (which==1){ g=g_kx; bb=b_kx; }
    else if (which==2){ g=g_qa; bb=b_qa; }
    else { g=g_ka; bb=b_ka; }

    const int t = threadIdx.x;
    const int h = h0 + (t >> 7);
    const int d = t & 127;
    const size_t idx = ((size_t)(b_*NH + h)*SEQ + n_)*DH + d;
    float v = bf2f(buf[idx]);
    float s1 = v, s2 = v*v;
    #pragma unroll
    for (int o=32;o>=1;o>>=1){
        s1 += __shfl_down(s1,o);
        s2 += __shfl_down(s2,o);
    }
    const int lane = t & 63, wv = t >> 6;
    if (lane==0){ red[wv]=s1; red[8+wv]=s2; }
    __syncthreads();
    float sum=0.f, sq=0.f;
    #pragma unroll
    for (int w=0;w<8;++w){ sum+=red[w]; sq+=red[8+w]; }
    const float mu = sum * (1.f/512.f);
    const float var = sq * (1.f/512.f) - mu*mu;
    const float rs = rsqrtf(var + 1e-5f);
    const float xn = (v - mu)*rs*g[t] + bb[t];
    vn[t] = xn;
    __syncthreads();
    const float partner = vn[t ^ 64];
    const float2 cssn = tab[(n_ << 6) + (d & 63)];
    const float rot = (d < 64) ? -partner : partner;
    float val = xn*cssn.x + rot*cssn.y;
    // fold 1/sqrt(128) * log2(e) into Q (softmax runs in exp2 domain)
    if (!(which & 1)) val *= 0.08838834764831845f * 1.4426950408889634f;
    ob[idx] = f2bf(val);
}

// ---------------- Kernel 3: 32x32 MFMA flash attention, reg-V + K-only LDS ----------
__global__ __launch_bounds__(256,2) void attn_mfma(
    const unsigned short* __restrict__ Qb, const unsigned short* __restrict__ Kb,
    const unsigned short* __restrict__ Vf, float* __restrict__ out)
{
    __shared__ __align__(16) unsigned short SMEM[17920];   // 35KB

    // XCD-aware remap: blocks sharing (b,h) land on one XCD
    const int nblk = blockIdx.x;
    const int jj  = nblk >> 3;
    const int bh  = (nblk & 7)*4 + (jj >> 4);
    const int q0  = (jj & 15) * 64;

    const int tid = threadIdx.x;
    const int w   = tid >> 6;
    const int qg  = w >> 1;      // q-group: rows q0+qg*32 .. +31
    const int ks  = w & 1;       // K-tile parity
    const int l   = tid & 63;
    const int lq  = l & 31;      // q column / V d-column
    const int h   = l >> 5;      // k-half within fragments
    const size_t hoff = (size_t)bh * SEQ * DH;

    bf16x8 qf[8];
    {
        const unsigned short* qp = Qb + hoff + (size_t)(q0 + qg*32 + lq)*DH + h*8;
        #pragma unroll
        for (int dc=0;dc<8;++dc) qf[dc] = *(const bf16x8*)(qp + dc*16);
    }

    f32x16 o[4];
    #pragma unroll
    for (int dt=0;dt<4;++dt)
        #pragma unroll
        for (int i=0;i<16;++i) o[dt][i] = 0.f;
    float mrun = -INFINITY, lrun = 0.f;

    const unsigned short* kg0 = Kb + hoff;
    const unsigned short* vt0 = Vf + (size_t)bh*32*4096 + l*8;   // per-tile 4096 elems

    #define STAGE_K(bb, tp) { \
        unsigned short* kd0 = SMEM + ((bb)*2+0)*4096; \
        unsigned short* kd1 = SMEM + ((bb)*2+1)*4096; \
        const unsigned short* ks0_ = kg0 + (size_t)(2*(tp))*4096; \
        const unsigned short* ks1_ = kg0 + (size_t)(2*(tp)+1)*4096; \
        _Pragma("unroll") \
        for (int i_=0;i_<2;++i_){ \
            int f_ = tid + i_*256; int r_ = f_>>4, s_ = f_&15; \
            glds16(ks0_ + r_*128 + ((s_ ^ (r_&7))*8), kd0 + f_*8); \
        } \
        _Pragma("unroll") \
        for (int i_=0;i_<2;++i_){ \
            int f_ = tid + i_*256; int r_ = f_>>4, s_ = f_&15; \
            glds16(ks1_ + r_*128 + ((s_ ^ (r_&7))*8), kd1 + f_*8); \
        } }

    #define LOADV(VF_, tile) { \
        const unsigned short* vb_ = vt0 + (size_t)(tile)*4096; \
        _Pragma("unroll") \
        for (int kc_=0;kc_<2;++kc_) \
            _Pragma("unroll") \
            for (int dt_=0;dt_<4;++dt_) \
                VF_[kc_][dt_] = *(const bf16x8*)(vb_ + (kc_*4+dt_)*512); }

    bf16x8 vfA[2][4], vfB[2][4];

    STAGE_K(0, 0);
    LOADV(vfA, ks);
    asm volatile("s_waitcnt vmcnt(0)" ::: "memory");
    __builtin_amdgcn_s_barrier();

    int cur = 0;

    #define BODY(it, VFU, VFL) { \
        if ((it) < 15) STAGE_K(cur^1, (it)+1); \
        __builtin_amdgcn_sched_barrier(0); \
        if ((it) < 15) LOADV(VFL, 2*((it)+1)+ks); \
        const unsigned short* kb = SMEM + (cur*2+ks)*4096 + lq*128; \
        f32x16 s; \
        _Pragma("unroll") \
        for (int i=0;i<16;++i) s[i] = 0.f; \
        _Pragma("unroll") \
        for (int dc=0;dc<8;++dc){ \
            bf16x8 kf = *(const bf16x8*)(kb + (((dc*2+h) ^ (lq&7))*8)); \
            s = __builtin_amdgcn_mfma_f32_32x32x16_bf16(kf, qf[dc], s, 0,0,0); \
        } \
        float mx = fmaxf(s[0], s[1]); \
        _Pragma("unroll") \
        for (int i=2;i<16;++i) mx = fmaxf(mx, s[i]); \
        mx = fmaxf(mx, __shfl_xor(mx, 32)); \
        if (__any(mx > mrun + 8.f)){ \
            const float mn = fmaxf(mrun, mx); \
            const float al = __builtin_amdgcn_exp2f(mrun - mn); \
            mrun = mn; lrun *= al; \
            _Pragma("unroll") \
            for (int dt=0;dt<4;++dt) \
                _Pragma("unroll") \
                for (int i=0;i<16;++i) o[dt][i] *= al; \
        } \
        float su = 0.f; \
        _Pragma("unroll") \
        for (int i=0;i<16;++i){ s[i] = __builtin_amdgcn_exp2f(s[i]-mrun); su += s[i]; } \
        su += __shfl_xor(su, 32); \
        lrun += su; \
        bf16x8 pf[2]; \
        _Pragma("unroll") \
        for (int kc=0; kc<2; ++kc){ \
            const int b8 = kc*8; \
            unsigned A, Bq, Cq, Dq; \
            asm("v_cvt_pk_bf16_f32 %0, %1, %2" : "=v"(A)  : "v"(s[b8+0]), "v"(s[b8+1])); \
            asm("v_cvt_pk_bf16_f32 %0, %1, %2" : "=v"(Bq) : "v"(s[b8+2]), "v"(s[b8+3])); \
            asm("v_cvt_pk_bf16_f32 %0, %1, %2" : "=v"(Cq) : "v"(s[b8+4]), "v"(s[b8+5])); \
            asm("v_cvt_pk_bf16_f32 %0, %1, %2" : "=v"(Dq) : "v"(s[b8+6]), "v"(s[b8+7])); \
            asm("v_permlane32_swap_b32 %0, %1" : "+v"(A),  "+v"(Cq)); \
            asm("v_permlane32_swap_b32 %0, %1" : "+v"(Bq), "+v"(Dq)); \
            union { unsigned u[4]; bf16x8 v; } pk; \
            pk.u[0] = A; pk.u[1] = Bq; pk.u[2] = Cq; pk.u[3] = Dq; \
            pf[kc] = pk.v; \
        } \
        _Pragma("unroll") \
        for (int kc=0;kc<2;++kc) \
            _Pragma("unroll") \
            for (int dt=0;dt<4;++dt) \
                o[dt] = __builtin_amdgcn_mfma_f32_32x32x16_bf16(VFU[kc][dt], pf[kc], o[dt], 0,0,0); \
        if ((it) < 15){ \
            asm volatile("s_waitcnt vmcnt(8)" ::: "memory"); \
            __builtin_amdgcn_s_barrier(); \
            cur ^= 1; \
        } }

    for (int ii=0; ii<8; ++ii){
        BODY(2*ii,   vfA, vfB);
        BODY(2*ii+1, vfB, vfA);
    }
    #undef BODY
    #undef STAGE_K
    #undef LOADV

    // ---- epilogue: merge parity partials, transpose, store ----
    __syncthreads();
    float* Lm = (float*)SMEM;            // [2 qg][2 ks][32] running max
    float* Ll = Lm + 128;                // [2 qg][2 ks][32] running sum
    Lm[(qg*2+ks)*32 + lq] = mrun;
    Ll[(qg*2+ks)*32 + lq] = lrun;
    __syncthreads();
    const float mo  = Lm[(qg*2+(ks^1))*32 + lq];
    const float lo_ = Ll[(qg*2+(ks^1))*32 + lq];
    const float mf = fmaxf(mrun, mo);
    const float a  = __builtin_amdgcn_exp2f(mrun - mf);
    const float ao = __builtin_amdgcn_exp2f(mo - mf);
    const float lf = lrun*a + lo_*ao;
    float* Ob = (float*)SMEM + 512 + qg*4160;   // [32 q][stride 129] f32
    if (ks == 1){
        #pragma unroll
        for (int dt=0;dt<4;++dt)
            #pragma unroll
            for (int r=0;r<16;++r){
                const int d = dt*32 + (r&3) + 8*(r>>2) + 4*h;
                Ob[lq*129 + d] = o[dt][r]*a;
            }
    }
    __syncthreads();
    if (ks == 0){
        const float inv = 1.0f/lf;
        #pragma unroll
        for (int dt=0;dt<4;++dt)
            #pragma unroll
            for (int r=0;r<16;++r){
                const int d = dt*32 + (r&3) + 8*(r>>2) + 4*h;
                const int idx = lq*129 + d;
                Ob[idx] = (o[dt][r]*a + Ob[idx])*inv;
            }
    }
    __syncthreads();
    const int b_ = bh >> 3, h_ = bh & 7;
    const int row = tid >> 2, quarter = tid & 3;
    const float* src = (const float*)SMEM + 512 + (row>>5)*4160 + (row&31)*129 + quarter*32;
    float* dst = out + ((size_t)(b_*SEQ) + q0 + row)*1024 + h_*128 + quarter*32;
    #pragma unroll
    for (int j=0;j<8;++j)
        *(float4*)(dst + j*4) = *(const float4*)(src + j*4);
}

extern "C" void kernel_launch(void* const* d_in, const int* in_sizes, int n_in,
                              void* d_out, int out_size, void* d_ws, size_t ws_size,
                              hipStream_t stream) {
    const float* x    = (const float*)d_in[0];
    const float* a    = (const float*)d_in[1];
    const float* Wx   = (const float*)d_in[2];
    const float* Wa   = (const float*)d_in[3];
    const float* g_qx = (const float*)d_in[4];
    const float* b_qx = (const float*)d_in[5];
    const float* g_kx = (const float*)d_in[6];
    const float* b_kx = (const float*)d_in[7];
    const float* g_qa = (const float*)d_in[8];
    const float* b_qa = (const float*)d_in[9];
    const float* g_ka = (const float*)d_in[10];
    const float* b_ka = (const float*)d_in[11];
    float* out = (float*)d_out;

    const size_t E = (size_t)BB*NH*SEQ*DH;        // 4,194,304 elements
    unsigned short* wsqb = (unsigned short*)d_ws; // 8MB bf16 pre-LN q
    unsigned short* wskb = wsqb + E;              // 8MB bf16 pre-LN k
    unsigned short* Vf   = wskb + E;              // 8MB fragment-major V
    unsigned short* region = Vf + E;
    unsigned short* Ab  = region;                 // 8MB (gemm phase)
    unsigned short* Qb  = region;                 // 8MB (attn phase, overlays Ab)
    unsigned short* Kb  = region + E;             // 8MB
    unsigned short* Bhi = region + 2*E;           // 3MB
    unsigned short* Blo = Bhi + (size_t)2*64*1536*8;  // 3MB
    float2* tab = (float2*)(Blo + (size_t)2*64*1536*8);  // 512KB

    prep_a<<<dim3(16, 64, 2), 256, 0, stream>>>(x, a, Ab);
    prep_b<<<dim3(7, 64, 2), 256, 0, stream>>>(Wx, Wa, Bhi, Blo, tab);
    qkv_mfma<<<dim3(32, 12, 2), 256, 0, stream>>>(Ab, Bhi, Blo, wsqb, wskb, Vf);
    ln_rope<<<dim3(MROWS, 4), 512, 0, stream>>>(wsqb, wskb, Qb, Kb, tab,
        g_qx, b_qx, g_kx, b_kx, g_qa, b_qa, g_ka, b_ka);
    attn_mfma<<<dim3(512), 256, 0, stream>>>(Qb, Kb, Vf, out);
}

// Round 12
// 73.907 us; speedup vs baseline: 1.4428x; 1.2583x over previous
//
#include <hip/hip_runtime.h>
#include <math.h>

typedef __attribute__((ext_vector_type(8))) short bf16x8;
typedef __attribute__((ext_vector_type(4))) short bf16x4;
typedef __attribute__((ext_vector_type(4))) float f32x4;
typedef __attribute__((ext_vector_type(16))) float f32x16;

#define BB    4
#define SEQ   1024
#define DIMV  512
#define TD    1536
#define NH    8
#define DH    128
#define MROWS (BB*SEQ)

__device__ inline unsigned short f2bf(float x){
    union { float f; unsigned u; } v; v.f = x;
    unsigned r = v.u + 0x7FFF + ((v.u >> 16) & 1);   // RNE
    return (unsigned short)(r >> 16);
}
__device__ inline float bf2f(unsigned short h){
    union { unsigned u; float f; } v; v.u = ((unsigned)h) << 16; return v.f;
}

__device__ inline void glds16(const void* g, void* l){
    __builtin_amdgcn_global_load_lds(
        (const __attribute__((address_space(1))) unsigned int*)g,
        (__attribute__((address_space(3))) unsigned int*)l,
        16, 0, 0);
}

// ---------------- Prep A: x|a -> bf16, K-granule-major ----------------
__global__ __launch_bounds__(256) void prep_a(
    const float* __restrict__ X, const float* __restrict__ A,
    unsigned short* __restrict__ Ab)
{
    const int m   = blockIdx.x*256 + threadIdx.x;
    const int pg  = blockIdx.y;         // p*4+g  (0..63)
    const int mat = blockIdx.z;
    const float* In = mat ? A : X;
    const float* src = In + (size_t)m*DIMV + pg*8;
    float4 v0 = *(const float4*)src;
    float4 v1 = *(const float4*)(src+4);
    float v[8] = {v0.x,v0.y,v0.z,v0.w,v1.x,v1.y,v1.z,v1.w};
    bf16x8 h;
    #pragma unroll
    for (int j=0;j<8;++j) h[j] = (short)f2bf(v[j]);
    const size_t o = ((size_t)(mat*64 + pg)*4096 + m)*8;
    *(bf16x8*)(Ab+o) = h;
}

// ------- Prep B: transpose+split W into hi/lo bf16 (x-block 6 builds RoPE table) -----
__global__ __launch_bounds__(256) void prep_b(
    const float* __restrict__ Wx, const float* __restrict__ Wa,
    unsigned short* __restrict__ Bhi, unsigned short* __restrict__ Blo,
    float2* __restrict__ tab)
{
    if (blockIdx.x == 6){
        const int i = (blockIdx.z*64 + blockIdx.y)*256 + threadIdx.x;   // 0..32767
        #pragma unroll
        for (int k=0;k<2;++k){
            const int idx = i + k*32768;
            const int n = idx >> 6, dd = idx & 63;
            const float inv = expf((float)dd * (1.f/64.f) * -9.210340371976184f);
            const float ang = (float)n * inv;
            float sn, cs;
            sincosf(ang, &sn, &cs);
            tab[idx] = make_float2(cs, sn);
        }
        return;
    }
    const int n   = blockIdx.x*256 + threadIdx.x;
    const int pg  = blockIdx.y;
    const int mat = blockIdx.z;
    const float* W = mat ? Wa : Wx;
    bf16x8 h, l;
    #pragma unroll
    for (int j=0;j<8;++j){
        float v = W[(size_t)(pg*8 + j)*TD + n];
        unsigned short hb = f2bf(v);
        h[j] = (short)hb;
        l[j] = (short)f2bf(v - bf2f(hb));
    }
    const size_t o = ((size_t)(mat*64 + pg)*1536 + n)*8;
    *(bf16x8*)(Bhi+o) = h;
    *(bf16x8*)(Blo+o) = l;
}

// ---------------- Kernel 1: QKV GEMM via bf16 MFMA, BK=64 ----------------
// V blocks (bn>=1024): 2-pass W hi/lo. Q/K blocks: 1-pass bf16 W.
__global__ __launch_bounds__(256,3) void qkv_mfma(
    const unsigned short* __restrict__ Ab,
    const unsigned short* __restrict__ Bhi, const unsigned short* __restrict__ Blo,
    unsigned short* __restrict__ wsqb, unsigned short* __restrict__ wskb,
    unsigned short* __restrict__ Vf)
{
    __shared__ __align__(16) unsigned short sA [8192];
    __shared__ __align__(16) unsigned short sBh[8192];
    __shared__ __align__(16) unsigned short sBl[8192];

    const int mat = blockIdx.z;
    const int bm  = blockIdx.x * 128;
    const int bn  = blockIdx.y * 128;
    const bool vblk = (bn >= 1024);
    const int tid = threadIdx.x;
    const int w   = tid >> 6, l = tid & 63;
    const int wr  = w >> 1,  wc = w & 1;
    const int lg  = l >> 4,  ln = l & 15;

    f32x4 acc[4][4];
    #pragma unroll
    for (int i=0;i<4;++i)
        #pragma unroll
        for (int j=0;j<4;++j){ acc[i][j][0]=0.f; acc[i][j][1]=0.f; acc[i][j][2]=0.f; acc[i][j][3]=0.f; }

    const int g0 = tid >> 7, r0 = tid & 127;
    const size_t ASTEP = (size_t)8*4096*8;     // 8 granule-panels per K-step
    const size_t BSTEP = (size_t)8*1536*8;
    const unsigned short* aP = Ab  + ((size_t)(mat*64 + g0)*4096 + bm + r0)*8;
    const unsigned short* bPh = Bhi + ((size_t)(mat*64 + g0)*1536 + bn + r0)*8;
    const unsigned short* bPl = Blo + ((size_t)(mat*64 + g0)*1536 + bn + r0)*8;
    const size_t AC = (size_t)2*4096*8;        // per-c offset (2 panels)
    const size_t BC = (size_t)2*1536*8;

    if (vblk){
        for (int p=0; p<8; ++p){
            #pragma unroll
            for (int c=0;c<4;++c){
                glds16(aP  + c*AC, sA  + (c*256+tid)*8);
                glds16(bPh + c*BC, sBh + (c*256+tid)*8);
                glds16(bPl + c*BC, sBl + (c*256+tid)*8);
            }
            aP += ASTEP; bPh += BSTEP; bPl += BSTEP;
            __syncthreads();

            #pragma unroll
            for (int kk=0;kk<2;++kk){
                bf16x8 av[4], bh[4], bl[4];
                #pragma unroll
                for (int mi=0; mi<4; ++mi){
                    const int off = ((kk*4+lg)*128 + wr*64 + mi*16 + ln)*8;
                    av[mi] = *(const bf16x8*)(sA + off);
                }
                #pragma unroll
                for (int ni=0; ni<4; ++ni){
                    const int off = ((kk*4+lg)*128 + wc*64 + ni*16 + ln)*8;
                    bh[ni] = *(const bf16x8*)(sBh + off);
                    bl[ni] = *(const bf16x8*)(sBl + off);
                }
                #pragma unroll
                for (int mi=0; mi<4; ++mi)
                    #pragma unroll
                    for (int ni=0; ni<4; ++ni){
                        acc[mi][ni] = __builtin_amdgcn_mfma_f32_16x16x32_bf16(av[mi], bh[ni], acc[mi][ni], 0,0,0);
                        acc[mi][ni] = __builtin_amdgcn_mfma_f32_16x16x32_bf16(av[mi], bl[ni], acc[mi][ni], 0,0,0);
                    }
            }
            __syncthreads();
        }
    } else {
        for (int p=0; p<8; ++p){
            #pragma unroll
            for (int c=0;c<4;++c){
                glds16(aP  + c*AC, sA  + (c*256+tid)*8);
                glds16(bPh + c*BC, sBh + (c*256+tid)*8);
            }
            aP += ASTEP; bPh += BSTEP;
            __syncthreads();

            #pragma unroll
            for (int kk=0;kk<2;++kk){
                bf16x8 av[4], bh[4];
                #pragma unroll
                for (int mi=0; mi<4; ++mi){
                    const int off = ((kk*4+lg)*128 + wr*64 + mi*16 + ln)*8;
                    av[mi] = *(const bf16x8*)(sA + off);
                }
                #pragma unroll
                for (int ni=0; ni<4; ++ni){
                    const int off = ((kk*4+lg)*128 + wc*64 + ni*16 + ln)*8;
                    bh[ni] = *(const bf16x8*)(sBh + off);
                }
                #pragma unroll
                for (int mi=0; mi<4; ++mi)
                    #pragma unroll
                    for (int ni=0; ni<4; ++ni)
                        acc[mi][ni] = __builtin_amdgcn_mfma_f32_16x16x32_bf16(av[mi], bh[ni], acc[mi][ni], 0,0,0);
            }
            __syncthreads();
        }
    }

    const int b_ = bm >> 10;
    const int n0base = (bm & 1023) + wr*64;
    const int colB = bn + wc*64;
    if (!vblk){
        unsigned short* base = (colB < 512) ? wsqb : wskb;
        #pragma unroll
        for (int ni=0; ni<4; ++ni){
            const int col = colB + ni*16 + ln;
            const int h = mat*4 + ((col >> 7) & 3);
            const int d = col & 127;
            #pragma unroll
            for (int mi=0; mi<4; ++mi){
                const int n0 = n0base + mi*16 + lg*4;
                unsigned short* dst = base + ((size_t)(b_*NH + h)*SEQ + n0)*DH + d;
                #pragma unroll
                for (int r=0;r<4;++r) dst[r*DH] = f2bf(acc[mi][ni][r]);
            }
        }
    } else {
        // V -> fragment-major: Vf[((bh*32+kt)*2+kc)*4+dt][lane][8]
        #pragma unroll
        for (int ni=0; ni<4; ++ni){
            const int col = colB + ni*16 + ln;
            const int h  = mat*4 + ((col >> 7) & 3);
            const int d  = col & 127;
            const int dt = d >> 5;
            const int lane = (d & 31) + 32*(lg >> 1);
            const int bh = b_*NH + h;
            #pragma unroll
            for (int mi=0; mi<4; ++mi){
                const int kt = (n0base + mi*16) >> 5;
                const int kc = mi & 1;
                unsigned short* dst = Vf +
                    ((((size_t)(bh*32 + kt)*2 + kc)*4 + dt)*64 + lane)*8 + (lg&1)*4;
                bf16x4 pk;
                #pragma unroll
                for (int r=0;r<4;++r) pk[r] = (short)f2bf(acc[mi][ni][r]);
                *(bf16x4*)dst = pk;
            }
        }
    }
}

// ---------------- Kernel 2: LayerNorm + RoPE, wave-per-row (no LDS/barriers) --------
__global__ __launch_bounds__(256) void ln_rope(
    const unsigned short* __restrict__ wsqb, const unsigned short* __restrict__ wskb,
    unsigned short* __restrict__ Qb, unsigned short* __restrict__ Kb,
    const float2* __restrict__ tab,
    const float* __restrict__ g_qx, const float* __restrict__ b_qx,
    const float* __restrict__ g_kx, const float* __restrict__ b_kx,
    const float* __restrict__ g_qa, const float* __restrict__ b_qa,
    const float* __restrict__ g_ka, const float* __restrict__ b_ka)
{
    const int w0   = threadIdx.x >> 6;
    const int lane = threadIdx.x & 63;
    const int inst = blockIdx.x*4 + w0;        // 0..16383
    const int which = inst & 3;                // 4 whiches of same row share block
    const int r = inst >> 2;
    const int b_ = r >> 10, n_ = r & 1023;

    const unsigned short* buf = (which & 1) ? wskb : wsqb;
    unsigned short* ob = (which & 1) ? Kb : Qb;
    const int h0 = (which >> 1) ? 4 : 0;
    const float* g; const float* bb;
    if (which==0){ g=g_qx; bb=b_qx; }
    else if (which==1){ g=g_kx; bb=b_kx; }
    else if (which==2){ g=g_qa; bb=b_qa; }
    else { g=g_ka; bb=b_ka; }

    const int hc = lane >> 4;                  // head chunk 0..3
    const int h  = h0 + hc;
    const int d0 = (lane & 15) * 8;            // within-head d base
    const size_t idx = ((size_t)(b_*NH + h)*SEQ + n_)*DH + d0;

    bf16x8 vin = *(const bf16x8*)(buf + idx);
    float v[8];
    float s1 = 0.f, s2 = 0.f;
    #pragma unroll
    for (int j=0;j<8;++j){
        v[j] = bf2f((unsigned short)vin[j]);
        s1 += v[j]; s2 += v[j]*v[j];
    }
    #pragma unroll
    for (int off=1; off<64; off<<=1){
        s1 += __shfl_xor(s1, off);
        s2 += __shfl_xor(s2, off);
    }
    const float mu = s1 * (1.f/512.f);
    const float var = s2 * (1.f/512.f) - mu*mu;
    const float rs = rsqrtf(var + 1e-5f);

    const int e = lane*8;
    float4 gv0 = *(const float4*)(g + e);
    float4 gv1 = *(const float4*)(g + e + 4);
    float4 bv0 = *(const float4*)(bb + e);
    float4 bv1 = *(const float4*)(bb + e + 4);
    const float gg[8]  = {gv0.x,gv0.y,gv0.z,gv0.w,gv1.x,gv1.y,gv1.z,gv1.w};
    const float bbv[8] = {bv0.x,bv0.y,bv0.z,bv0.w,bv1.x,bv1.y,bv1.z,bv1.w};

    float xn[8];
    #pragma unroll
    for (int j=0;j<8;++j) xn[j] = (v[j]-mu)*rs*gg[j] + bbv[j];

    float pr[8];
    #pragma unroll
    for (int j=0;j<8;++j) pr[j] = __shfl_xor(xn[j], 8);   // partner: d ^ 64  <=> lane ^ 8

    const bool firsthalf = (lane & 8) == 0;
    const float2* tp = tab + (n_ << 6) + (lane & 7)*8;
    const float qs = 0.08838834764831845f * 1.4426950408889634f;
    bf16x8 outv;
    #pragma unroll
    for (int j=0;j<8;++j){
        const float2 cs = tp[j];
        const float rot = firsthalf ? -pr[j] : pr[j];
        float val = xn[j]*cs.x + rot*cs.y;
        if (!(which & 1)) val *= qs;           // fold 1/sqrt(128)*log2e into Q
        outv[j] = (short)f2bf(val);
    }
    *(bf16x8*)(ob + idx) = outv;
}

// ---------------- Kernel 3: 32x32 MFMA flash attention, 64 keys/phase ----------------
// 4 waves (qg, ks). K ring: 2 slots x 4 tiles (64KB) via global_load_lds, staged one
// phase ahead. V single-buffered per phase: issued at top, consumed after softmax
// (register-dependency waits leave the younger K-glds in flight). 1 barrier/64 keys.
__global__ __launch_bounds__(256,2) void attn_mfma(
    const unsigned short* __restrict__ Qb, const unsigned short* __restrict__ Kb,
    const unsigned short* __restrict__ Vf, float* __restrict__ out)
{
    __shared__ __align__(16) unsigned short SMEM[32768];   // 64KB

    // XCD-aware remap: blocks sharing (b,h) land on one XCD
    const int nblk = blockIdx.x;
    const int jj  = nblk >> 3;
    const int bh  = (nblk & 7)*4 + (jj >> 4);
    const int q0  = (jj & 15) * 64;

    const int tid = threadIdx.x;
    const int w   = tid >> 6;
    const int qg  = w >> 1;      // q-group: rows q0+qg*32 .. +31
    const int ks  = w & 1;       // K-tile parity
    const int l   = tid & 63;
    const int lq  = l & 31;      // q column / V d-column
    const int h   = l >> 5;      // k-half within fragments
    const size_t hoff = (size_t)bh * SEQ * DH;

    bf16x8 qf[8];
    {
        const unsigned short* qp = Qb + hoff + (size_t)(q0 + qg*32 + lq)*DH + h*8;
        #pragma unroll
        for (int dc=0;dc<8;++dc) qf[dc] = *(const bf16x8*)(qp + dc*16);
    }

    f32x16 o[4];
    #pragma unroll
    for (int dt=0;dt<4;++dt)
        #pragma unroll
        for (int i=0;i<16;++i) o[dt][i] = 0.f;
    float mrun = -INFINITY, lrun = 0.f;

    const unsigned short* kg0 = Kb + hoff;
    const unsigned short* vt0 = Vf + (size_t)bh*32*4096 + l*8;   // per-tile 4096 elems

    // Stage tile group grp (tiles 4*grp .. 4*grp+3) into ring slot bb (16K shorts).
    #define STAGE_K(bb, grp) { \
        unsigned short* base_ = SMEM + (bb)*16384; \
        const unsigned short* ks_ = kg0 + (size_t)(4*(grp))*4096; \
        _Pragma("unroll") \
        for (int t_=0;t_<4;++t_) \
            _Pragma("unroll") \
            for (int i_=0;i_<2;++i_){ \
                int f_ = tid + i_*256; int r_ = f_>>4, s_ = f_&15; \
                glds16(ks_ + t_*4096 + r_*128 + ((s_ ^ (r_&7))*8), base_ + t_*4096 + f_*8); \
            } }

    #define LOADV(VF_, tile) { \
        const unsigned short* vb_ = vt0 + (size_t)(tile)*4096; \
        _Pragma("unroll") \
        for (int kc_=0;kc_<2;++kc_) \
            _Pragma("unroll") \
            for (int dt_=0;dt_<4;++dt_) \
                VF_[kc_][dt_] = *(const bf16x8*)(vb_ + (kc_*4+dt_)*512); }

    // One 32-key sub-phase: S from LDS slot, online softmax, in-register P, PV.
    #define SUB(slot, VF_) { \
        const unsigned short* kb = SMEM + cur*16384 + (slot)*4096 + lq*128; \
        f32x16 s; \
        _Pragma("unroll") \
        for (int i=0;i<16;++i) s[i] = 0.f; \
        _Pragma("unroll") \
        for (int dc=0;dc<8;++dc){ \
            bf16x8 kf = *(const bf16x8*)(kb + (((dc*2+h) ^ (lq&7))*8)); \
            s = __builtin_amdgcn_mfma_f32_32x32x16_bf16(kf, qf[dc], s, 0,0,0); \
        } \
        float mx = fmaxf(s[0], s[1]); \
        _Pragma("unroll") \
        for (int i=2;i<16;++i) mx = fmaxf(mx, s[i]); \
        mx = fmaxf(mx, __shfl_xor(mx, 32)); \
        if (__any(mx > mrun + 8.f)){ \
            const float mn = fmaxf(mrun, mx); \
            const float al = __builtin_amdgcn_exp2f(mrun - mn); \
            mrun = mn; lrun *= al; \
            _Pragma("unroll") \
            for (int dt=0;dt<4;++dt) \
                _Pragma("unroll") \
                for (int i=0;i<16;++i) o[dt][i] *= al; \
        } \
        float su = 0.f; \
        _Pragma("unroll") \
        for (int i=0;i<16;++i){ s[i] = __builtin_amdgcn_exp2f(s[i]-mrun); su += s[i]; } \
        su += __shfl_xor(su, 32); \
        lrun += su; \
        bf16x8 pf[2]; \
        _Pragma("unroll") \
        for (int kc=0; kc<2; ++kc){ \
            const int b8 = kc*8; \
            unsigned A, Bq, Cq, Dq; \
            asm("v_cvt_pk_bf16_f32 %0, %1, %2" : "=v"(A)  : "v"(s[b8+0]), "v"(s[b8+1])); \
            asm("v_cvt_pk_bf16_f32 %0, %1, %2" : "=v"(Bq) : "v"(s[b8+2]), "v"(s[b8+3])); \
            asm("v_cvt_pk_bf16_f32 %0, %1, %2" : "=v"(Cq) : "v"(s[b8+4]), "v"(s[b8+5])); \
            asm("v_cvt_pk_bf16_f32 %0, %1, %2" : "=v"(Dq) : "v"(s[b8+6]), "v"(s[b8+7])); \
            asm("v_permlane32_swap_b32 %0, %1" : "+v"(A),  "+v"(Cq)); \
            asm("v_permlane32_swap_b32 %0, %1" : "+v"(Bq), "+v"(Dq)); \
            union { unsigned u[4]; bf16x8 v; } pk; \
            pk.u[0] = A; pk.u[1] = Bq; pk.u[2] = Cq; pk.u[3] = Dq; \
            pf[kc] = pk.v; \
        } \
        _Pragma("unroll") \
        for (int kc=0;kc<2;++kc) \
            _Pragma("unroll") \
            for (int dt=0;dt<4;++dt) \
                o[dt] = __builtin_amdgcn_mfma_f32_32x32x16_bf16(VF_[kc][dt], pf[kc], o[dt], 0,0,0); }

    bf16x8 vf0[2][4], vf1[2][4];

    STAGE_K(0, 0);
    __syncthreads();

    int cur = 0;
    for (int ii=0; ii<8; ++ii){
        LOADV(vf0, 4*ii + ks);
        LOADV(vf1, 4*ii + 2 + ks);
        if (ii < 7) STAGE_K(cur^1, ii+1);
        SUB(ks,     vf0);
        SUB(2 + ks, vf1);
        __syncthreads();
        cur ^= 1;
    }
    #undef SUB
    #undef STAGE_K
    #undef LOADV

    // ---- epilogue: merge parity partials, transpose, store ----
    float* Lm = (float*)SMEM;            // [2 qg][2 ks][32] running max
    float* Ll = Lm + 128;                // [2 qg][2 ks][32] running sum
    Lm[(qg*2+ks)*32 + lq] = mrun;
    Ll[(qg*2+ks)*32 + lq] = lrun;
    __syncthreads();
    const float mo  = Lm[(qg*2+(ks^1))*32 + lq];
    const float lo_ = Ll[(qg*2+(ks^1))*32 + lq];
    const float mf = fmaxf(mrun, mo);
    const float a  = __builtin_amdgcn_exp2f(mrun - mf);
    const float ao = __builtin_amdgcn_exp2f(mo - mf);
    const float lf = lrun*a + lo_*ao;
    float* Ob = (float*)SMEM + 512 + qg*4160;   // [32 q][stride 129] f32
    if (ks == 1){
        #pragma unroll
        for (int dt=0;dt<4;++dt)
            #pragma unroll
            for (int r=0;r<16;++r){
                const int d = dt*32 + (r&3) + 8*(r>>2) + 4*h;
                Ob[lq*129 + d] = o[dt][r]*a;
            }
    }
    __syncthreads();
    if (ks == 0){
        const float inv = 1.0f/lf;
        #pragma unroll
        for (int dt=0;dt<4;++dt)
            #pragma unroll
            for (int r=0;r<16;++r){
                const int d = dt*32 + (r&3) + 8*(r>>2) + 4*h;
                const int idx = lq*129 + d;
                Ob[idx] = (o[dt][r]*a + Ob[idx])*inv;
            }
    }
    __syncthreads();
    const int b_ = bh >> 3, h_ = bh & 7;
    const int row = tid >> 2, quarter = tid & 3;
    const float* src = (const float*)SMEM + 512 + (row>>5)*4160 + (row&31)*129 + quarter*32;
    float* dst = out + ((size_t)(b_*SEQ) + q0 + row)*1024 + h_*128 + quarter*32;
    #pragma unroll
    for (int j=0;j<8;++j)
        *(float4*)(dst + j*4) = *(const float4*)(src + j*4);
}

extern "C" void kernel_launch(void* const* d_in, const int* in_sizes, int n_in,
                              void* d_out, int out_size, void* d_ws, size_t ws_size,
                              hipStream_t stream) {
    const float* x    = (const float*)d_in[0];
    const float* a    = (const float*)d_in[1];
    const float* Wx   = (const float*)d_in[2];
    const float* Wa   = (const float*)d_in[3];
    const float* g_qx = (const float*)d_in[4];
    const float* b_qx = (const float*)d_in[5];
    const float* g_kx = (const float*)d_in[6];
    const float* b_kx = (const float*)d_in[7];
    const float* g_qa = (const float*)d_in[8];
    const float* b_qa = (const float*)d_in[9];
    const float* g_ka = (const float*)d_in[10];
    const float* b_ka = (const float*)d_in[11];
    float* out = (float*)d_out;

    const size_t E = (size_t)BB*NH*SEQ*DH;        // 4,194,304 elements
    unsigned short* wsqb = (unsigned short*)d_ws; // 8MB bf16 pre-LN q
    unsigned short* wskb = wsqb + E;              // 8MB bf16 pre-LN k
    unsigned short* Vf   = wskb + E;              // 8MB fragment-major V
    unsigned short* region = Vf + E;
    unsigned short* Ab  = region;                 // 8MB (gemm phase)
    unsigned short* Qb  = region;                 // 8MB (attn phase, overlays Ab)
    unsigned short* Kb  = region + E;             // 8MB
    unsigned short* Bhi = region + 2*E;           // 3MB
    unsigned short* Blo = Bhi + (size_t)2*64*1536*8;  // 3MB
    float2* tab = (float2*)(Blo + (size_t)2*64*1536*8);  // 512KB

    prep_a<<<dim3(16, 64, 2), 256, 0, stream>>>(x, a, Ab);
    prep_b<<<dim3(7, 64, 2), 256, 0, stream>>>(Wx, Wa, Bhi, Blo, tab);
    qkv_mfma<<<dim3(32, 12, 2), 256, 0, stream>>>(Ab, Bhi, Blo, wsqb, wskb, Vf);
    ln_rope<<<dim3(4096), 256, 0, stream>>>(wsqb, wskb, Qb, Kb, tab,
        g_qx, b_qx, g_kx, b_kx, g_qa, b_qa, g_ka, b_ka);
    attn_mfma<<<dim3(512), 256, 0, stream>>>(Qb, Kb, Vf, out);
}